// Round 6
// baseline (34458.719 us; speedup 1.0000x reference)
//
#include <hip/hip_runtime.h>

// ---------------------------------------------------------------------------
// R-Net forward on MI355X. Round 6: REGISTER-RESIDENT attn weights.
// Evidence R2/R3/R5: the attn recurrence is bound by streaming ~1MB of weights
// through one CU every step (not bytes, not FLOPs). Fix: pack all attn weights
// as f16x2 into VGPRs (248 dwords/thread x 1024 threads = full weight set per
// WG), Hmem in LDS; per step only ~4KB of activations move. One chain per WG,
// 32 WGs, v_dot2_f32_f16 accumulate in fp32, in-wave shfl reductions.
//   P=256, Q=48, B=16, H=128, D=556, 2H=256, 3H=384, 4H=512
// ---------------------------------------------------------------------------

#define PP 256
#define QQ 48
#define BB 16

typedef _Float16 f16;
typedef f16 f16x4 __attribute__((ext_vector_type(4)));
typedef f16 h2 __attribute__((ext_vector_type(2)));

__device__ __forceinline__ float fast_rcp(float x) { return __builtin_amdgcn_rcpf(x); }
__device__ __forceinline__ float tanh_f(float x) {
  float e = __expf(2.0f * x);
  return 1.0f - 2.0f * fast_rcp(1.0f + e);
}
__device__ __forceinline__ float sigm_f(float x) {
  return fast_rcp(1.0f + __expf(-x));
}
__device__ __forceinline__ float fdot2f(h2 a, h2 b, float c) {
#if defined(__has_builtin)
#if __has_builtin(__builtin_amdgcn_fdot2)
  return __builtin_amdgcn_fdot2(a, b, c, false);
#else
  return c + (float)a.x*(float)b.x + (float)a.y*(float)b.y;
#endif
#else
  return c + (float)a.x*(float)b.x + (float)a.y*(float)b.y;
#endif
}

// ---------------------------------------------------------------------------
// Generic C[M,N] = A[M,K] @ W[N,K]^T + bias.  64x64 tiles, BK=16, 256 thr.
// ---------------------------------------------------------------------------
__global__ __launch_bounds__(256) void gemm_nt(
    const float* __restrict__ A, int lda,
    const float* __restrict__ W, int ldw,
    const float* __restrict__ bias,
    float* __restrict__ C, int ldc, int K) {
  __shared__ float As[64][17];
  __shared__ float Ws[64][17];
  int tid = threadIdx.x;
  int m0 = blockIdx.x * 64, n0 = blockIdx.y * 64;
  int lr = tid >> 2, lq = (tid & 3) * 4;
  int tr = tid >> 4, tc = tid & 15;
  float acc[4][4] = {};
  for (int k0 = 0; k0 < K; k0 += 16) {
    float4 av = {0,0,0,0}, wv = {0,0,0,0};
    if (k0 + lq < K) {
      av = *(const float4*)&A[(size_t)(m0 + lr) * lda + k0 + lq];
      wv = *(const float4*)&W[(size_t)(n0 + lr) * ldw + k0 + lq];
    }
    __syncthreads();
    As[lr][lq+0] = av.x; As[lr][lq+1] = av.y; As[lr][lq+2] = av.z; As[lr][lq+3] = av.w;
    Ws[lr][lq+0] = wv.x; Ws[lr][lq+1] = wv.y; Ws[lr][lq+2] = wv.z; Ws[lr][lq+3] = wv.w;
    __syncthreads();
#pragma unroll
    for (int kk = 0; kk < 16; ++kk) {
      float a4[4], b4[4];
#pragma unroll
      for (int i = 0; i < 4; ++i) a4[i] = As[tr*4+i][kk];
#pragma unroll
      for (int j = 0; j < 4; ++j) b4[j] = Ws[tc*4+j][kk];
#pragma unroll
      for (int i = 0; i < 4; ++i)
#pragma unroll
        for (int j = 0; j < 4; ++j) acc[i][j] += a4[i] * b4[j];
    }
  }
#pragma unroll
  for (int i = 0; i < 4; ++i) {
    int m = m0 + tr*4 + i;
#pragma unroll
    for (int j = 0; j < 4; ++j) {
      int n = n0 + tc*4 + j;
      C[(size_t)m * ldc + n] = acc[i][j] + (bias ? bias[n] : 0.0f);
    }
  }
}

// ---------------------------------------------------------------------------
// Batched fp32 transposes (pointer-net weights)
// ---------------------------------------------------------------------------
struct TDesc { const float* src; float* dst; int R, C, ld, off; };
struct TDescs { TDesc d[5]; };

__global__ __launch_bounds__(256) void transpose_many(TDescs ds) {
  TDesc d = ds.d[blockIdx.y];
  int idx = blockIdx.x * 256 + threadIdx.x;
  if (idx < d.R * d.C) {
    int r = idx / d.C, cc = idx % d.C;
    d.dst[(size_t)cc * d.R + r] = d.src[(size_t)r * d.ld + d.off + cc];
  }
}

// ---------------------------------------------------------------------------
// fp32 -> fp16 k-major converts for GRU weights: dst[k*R + j] = src[j*ld + k]
// ---------------------------------------------------------------------------
struct GDesc { const float* src; f16* dst; int R, C, ld; };
struct GDescs { GDesc d[3]; };

__global__ __launch_bounds__(256) void conv_w16_many(GDescs ds) {
  GDesc d = ds.d[blockIdx.y];
  int idx = blockIdx.x * 256 + threadIdx.x;
  if (idx < d.R * d.C) {
    int j = idx / d.C, k = idx % d.C;
    d.dst[(size_t)k * d.R + j] = (f16)d.src[(size_t)j * d.ld + k];
  }
}

// ---------------------------------------------------------------------------
// fp32 [R][C] -> h2 [R][C/2] row-pair packs (attn weights; off = col offset)
// ---------------------------------------------------------------------------
struct PDesc { const float* src; h2* dst; int R, C, ld, off; };
struct PDescs { PDesc d[8]; };

__global__ __launch_bounds__(256) void pack_pairs_many(PDescs ds) {
  PDesc d = ds.d[blockIdx.y];
  int HP = d.C >> 1;
  int idx = blockIdx.x * 256 + threadIdx.x;
  if (idx < d.R * HP) {
    int r = idx / HP, p = idx % HP;
    h2 v;
    v.x = (f16)d.src[(size_t)r*d.ld + d.off + 2*p];
    v.y = (f16)d.src[(size_t)r*d.ld + d.off + 2*p + 1];
    d.dst[(size_t)r*HP + p] = v;
  }
}

// [T,16,D] fp32 -> [16,T,D] fp16  (grid = (T,16), block = D)
__global__ void conv_perm16(const float* __restrict__ src, f16* __restrict__ dst, int D) {
  int t = blockIdx.x, b = blockIdx.y, d = threadIdx.x;
  dst[((size_t)b*gridDim.x + t)*D + d] = (f16)src[((size_t)t*BB + b)*D + d];
}

// ---------------------------------------------------------------------------
// GRU recurrence, fp16 weights (unchanged from R5 — known good ~1.2ms total).
// ---------------------------------------------------------------------------
__global__ __launch_bounds__(512) void gru_rec(
    const float* __restrict__ gi_p, const float* __restrict__ gi_q,
    const f16* __restrict__ WhhH,   // [128][384] k-major fp16
    const float* __restrict__ bhh,  // [384]
    float* __restrict__ out_p, float* __restrict__ out_q,
    float* __restrict__ Hp, float* __restrict__ Hq,
    int mode0, int finalmode) {
  int x = blockIdx.x;
  int seq = x >> 3, dir = (x >> 2) & 1, bg = x & 3;
  int T = seq ? QQ : PP;
  const float* gi = seq ? gi_q : gi_p;
  float* out = seq ? out_q : out_p;
  float* Hf  = seq ? Hq   : Hp;
  int b0 = bg * 4;
  int tid = threadIdx.x;
  __shared__ float hs[4][128];
  __shared__ float gpart[4][4][384];
  ((float*)hs)[tid] = 0.0f;
  __syncthreads();
  int ks = tid / 96;
  int jq = (tid % 96) * 4;
  int gb = tid >> 7, gj = tid & 127;
  for (int t = 0; t < T; ++t) {
    if (tid < 384) {
      float a[4][4] = {};
      const f16* wp = WhhH + (size_t)ks*32*384 + jq;
      const int kb = ks*32;
#pragma unroll 8
      for (int k = 0; k < 32; ++k) {
        f16x4 wv = *(const f16x4*)&wp[(size_t)k*384];
        float w0 = (float)wv[0], w1 = (float)wv[1], w2 = (float)wv[2], w3 = (float)wv[3];
#pragma unroll
        for (int bb = 0; bb < 4; ++bb) {
          float hv = hs[bb][kb + k];
          a[bb][0] += hv*w0; a[bb][1] += hv*w1; a[bb][2] += hv*w2; a[bb][3] += hv*w3;
        }
      }
#pragma unroll
      for (int bb = 0; bb < 4; ++bb) {
        gpart[ks][bb][jq+0]=a[bb][0]; gpart[ks][bb][jq+1]=a[bb][1];
        gpart[ks][bb][jq+2]=a[bb][2]; gpart[ks][bb][jq+3]=a[bb][3];
      }
    }
    __syncthreads();
    {
      size_t base;
      if (mode0) {
        int girow = dir ? (T-1-t) : t;
        base = ((size_t)girow*BB + b0+gb)*384;
      } else {
        base = (((size_t)dir*T + t)*BB + b0+gb)*384;
      }
      float ghr = bhh[gj]     + gpart[0][gb][gj]     + gpart[1][gb][gj]     + gpart[2][gb][gj]     + gpart[3][gb][gj];
      float ghz = bhh[128+gj] + gpart[0][gb][128+gj] + gpart[1][gb][128+gj] + gpart[2][gb][128+gj] + gpart[3][gb][128+gj];
      float ghn = bhh[256+gj] + gpart[0][gb][256+gj] + gpart[1][gb][256+gj] + gpart[2][gb][256+gj] + gpart[3][gb][256+gj];
      float gr = gi[base + gj], gz = gi[base + 128 + gj], gn = gi[base + 256 + gj];
      float r = sigm_f(gr + ghr);
      float z = sigm_f(gz + ghz);
      float n = tanh_f(gn + r * ghn);
      float h2v = (1.0f - z) * n + z * hs[gb][gj];
      hs[gb][gj] = h2v;
      if (finalmode) {
        int orow = dir ? (T-1-t) : t;
        Hf[((size_t)orow*BB + b0+gb)*256 + dir*128 + gj] = h2v;
      } else {
        out[(((size_t)dir*T + t)*BB + b0+gb)*128 + gj] = h2v;
      }
    }
    __syncthreads();
  }
}

// ---------------------------------------------------------------------------
// Register-resident gated-attention LSTM. 32 WGs = {dir}x{b}, 1024 threads.
// Weight slices live in VGPRs (f16x2) for the whole dispatch; Hmem in LDS;
// fp32 state/accumulate; only zg rounds to f16 (gate-input pack for dot2).
// ---------------------------------------------------------------------------
template<int QM>
__global__ __launch_bounds__(1024) void attn_reg(
    const float* __restrict__ Hseq,   // [256,16,256] fp32
    const h2*   __restrict__ Hmem2,   // [16][QM][128] pairs (f16)
    const h2*   __restrict__ att2,    // [16][QM][64]  pairs (f16)
    const float* __restrict__ Xcur,   // [256,16,128]
    const float* __restrict__ Xg,     // [256,16,512]
    const float* __restrict__ watt,   // [128]
    const h2*   __restrict__ WhidP,   // [128][64]  row-pair packed
    const h2*   __restrict__ WgwP,    // [512][128]
    const h2*   __restrict__ WihP,    // [512][256]
    const h2*   __restrict__ WhhP,    // [512][64]
    const float* __restrict__ bias,   // [512]
    float* __restrict__ Hy) {         // [256,16,256]
  constexpr int QSLOT = (QM == 48) ? 64 : 256;
  constexpr int HSPL  = 1024 / QSLOT;   // 16 or 4
  constexpr int PB    = 64 / HSPL;      // 4 or 16  (att pairs/thread)
  constexpr int DQ    = QM / 8;         // stage-D q iters
  const int dir = blockIdx.x >> 4, b = blockIdx.x & 15;
  const int tid = threadIdx.x;
  const int jo = tid >> 4, ks = tid & 15;      // stages E,G
  const int ja = tid & 127, ksp = tid >> 7;    // stage A
  const int qB = tid / HSPL, hsp = tid % HSPL; // stage B
  const int dD = tid & 127, qs = tid >> 7;     // stage D

  __shared__ h2   membP[QM * 128];   // Hmem pairs: 128KB (self) / 24KB (match)
  __shared__ float pA[8][128];
  __shared__ float pD[8][256];
  __shared__ float xhS[128];
  __shared__ float waS[128];
  __shared__ float peS[QSLOT];
  __shared__ float wF[256];
  __shared__ float uS[512];
  __shared__ h2   zgP[256];
  __shared__ float gS[512];
  __shared__ float hF[128], cF[128];
  __shared__ float biasS[512];
  __shared__ float denS;

  // ---- one-time register fills (248 dwords/thread) ----
  h2 WihR[8][16], WgwR[8][8], WhhR[8][4], WhidR[8], attR[PB];
#pragma unroll
  for (int c = 0; c < 8; ++c) {
    int j = jo*8 + c;
#pragma unroll
    for (int i = 0; i < 16; ++i) WihR[c][i] = WihP[(size_t)j*256 + ks + 16*i];
#pragma unroll
    for (int i = 0; i < 8; ++i)  WgwR[c][i] = WgwP[(size_t)j*128 + ks + 16*i];
#pragma unroll
    for (int i = 0; i < 4; ++i)  WhhR[c][i] = WhhP[(size_t)j*64 + ks + 16*i];
  }
#pragma unroll
  for (int i = 0; i < 8; ++i) WhidR[i] = WhidP[(size_t)ja*64 + ksp + 8*i];
#pragma unroll
  for (int i = 0; i < PB; ++i) {
    h2 v; v.x = (f16)0.0f; v.y = (f16)0.0f;
    if (qB < QM) v = att2[((size_t)b*QM + qB)*64 + hsp + HSPL*i];
    attR[i] = v;
  }
  for (int idx = tid; idx < QM*128; idx += 1024)
    membP[idx] = Hmem2[(size_t)b*QM*128 + idx];
  if (tid < 128) { waS[tid] = watt[tid]; hF[tid] = 0.0f; cF[tid] = 0.0f; }
  if (tid < 512) biasS[tid] = bias[tid];
  __syncthreads();

  for (int t = 0; t < PP; ++t) {
    const int row = dir ? (PP-1-t) : t;
    // early global loads for this step (consumed in stages A/F)
    float xcurv = 0.0f; float2 hs2 = make_float2(0.f,0.f), xg2 = make_float2(0.f,0.f);
    if (tid < 128) {
      xcurv = Xcur[((size_t)row*BB + b)*128 + tid];
      hs2 = *(const float2*)&Hseq[((size_t)row*BB + b)*256 + 2*tid];
    }
    if (tid < 256) xg2 = *(const float2*)&Xg[((size_t)row*BB + b)*512 + 2*tid];
    // ---- Stage A-partial: pA[ksp][ja] = h-slice @ Whid^T (fp32 unpack) ----
    {
      float acc = 0.0f;
#pragma unroll
      for (int i = 0; i < 8; ++i) {
        int kp = ksp + 8*i;
        h2 wv = WhidR[i];
        acc += (float)wv.x * hF[2*kp] + (float)wv.y * hF[2*kp+1];
      }
      pA[ksp][ja] = acc;
    }
    __syncthreads();
    if (tid < 128) {  // ---- A-combine: xh ----
      float a = xcurv;
#pragma unroll
      for (int i = 0; i < 8; ++i) a += pA[i][tid];
      xhS[tid] = a;
    }
    __syncthreads();
    // ---- Stage B: scores + exp ----
    {
      float s = 0.0f;
      if (qB < QM) {
#pragma unroll
        for (int i = 0; i < PB; ++i) {
          int hp = hsp + HSPL*i;
          h2 av = attR[i];
          float t0 = tanh_f((float)av.x + xhS[2*hp]);
          float t1 = tanh_f((float)av.y + xhS[2*hp+1]);
          s += waS[2*hp]*t0 + waS[2*hp+1]*t1;
        }
      }
#pragma unroll
      for (int m = 1; m < HSPL; m <<= 1) s += __shfl_xor(s, m);
      if (hsp == 0) peS[qB] = (qB < QM) ? __expf(s) : 0.0f;
    }
    __syncthreads();
    // ---- Stage D-partial: pw over q-slices ----
    {
      float a0 = 0.0f, a1 = 0.0f;
#pragma unroll
      for (int i = 0; i < DQ; ++i) {
        int q = qs + 8*i;
        float pv = peS[q];
        h2 mv = membP[q*128 + dD];
        a0 += pv * (float)mv.x; a1 += pv * (float)mv.y;
      }
      pD[qs][2*dD] = a0; pD[qs][2*dD+1] = a1;
    }
    __syncthreads();
    // ---- D-combine (wF unnormalized) + denominator ----
    if (tid < 256) {
      float a = 0.0f;
#pragma unroll
      for (int i = 0; i < 8; ++i) a += pD[i][tid];
      wF[tid] = a;
    } else if (tid < 320) {
      int l = tid - 256;
      float s = 0.0f;
#pragma unroll
      for (int i = 0; i < QSLOT/64; ++i) s += peS[l + 64*i];
#pragma unroll
      for (int m = 32; m; m >>= 1) s += __shfl_xor(s, m);
      if (l == 0) denS = s;
    }
    __syncthreads();
    // ---- Stage E: u = (w/den) @ Wgw^T (register weights, fp32 unpack) ----
    {
      float invd = fast_rcp(denS);
      float acc[8] = {};
#pragma unroll
      for (int i = 0; i < 8; ++i) {
        int kp = ks + 16*i;
        float w0 = wF[2*kp] * invd, w1 = wF[2*kp+1] * invd;
#pragma unroll
        for (int c = 0; c < 8; ++c) {
          h2 wv = WgwR[c][i];
          acc[c] += w0*(float)wv.x + w1*(float)wv.y;
        }
      }
#pragma unroll
      for (int m = 1; m < 16; m <<= 1) {
#pragma unroll
        for (int c = 0; c < 8; ++c) acc[c] += __shfl_xor(acc[c], m);
      }
      if (ks == 0) {
#pragma unroll
        for (int c = 0; c < 8; ++c) uS[jo*8 + c] = acc[c];
      }
    }
    __syncthreads();
    // ---- Stage F: zg = z * sigmoid(Xg + u), packed f16x2 ----
    if (tid < 256) {
      float invd = fast_rcp(denS);
      float z0, z1;
      if (tid < 128) { z0 = hs2.x; z1 = hs2.y; }
      else { z0 = wF[2*tid - 256] * invd; z1 = wF[2*tid - 255] * invd; }
      float zg0 = z0 * sigm_f(xg2.x + uS[2*tid]);
      float zg1 = z1 * sigm_f(xg2.y + uS[2*tid+1]);
      h2 p; p.x = (f16)zg0; p.y = (f16)zg1;
      zgP[tid] = p;
    }
    __syncthreads();
    // ---- Stage G: gates = zg @ Wih^T (dot2) + h @ Whh^T (fp32) ----
    {
      float acc[8] = {};
#pragma unroll
      for (int i = 0; i < 16; ++i) {
        h2 zv = zgP[ks + 16*i];
#pragma unroll
        for (int c = 0; c < 8; ++c) acc[c] = fdot2f(WihR[c][i], zv, acc[c]);
      }
#pragma unroll
      for (int i = 0; i < 4; ++i) {
        int kp = ks + 16*i;
        float h0 = hF[2*kp], h1 = hF[2*kp+1];
#pragma unroll
        for (int c = 0; c < 8; ++c) {
          h2 wv = WhhR[c][i];
          acc[c] += h0*(float)wv.x + h1*(float)wv.y;
        }
      }
#pragma unroll
      for (int m = 1; m < 16; m <<= 1) {
#pragma unroll
        for (int c = 0; c < 8; ++c) acc[c] += __shfl_xor(acc[c], m);
      }
      if (ks == 0) {
#pragma unroll
        for (int c = 0; c < 8; ++c) gS[jo*8 + c] = acc[c];
      }
    }
    __syncthreads();
    // ---- Stage H: LSTM cell (gate order i,f,g,o) ----
    if (tid < 128) {
      float gi2 = biasS[tid]     + gS[tid];
      float gf2 = biasS[128+tid] + gS[128+tid];
      float gg2 = biasS[256+tid] + gS[256+tid];
      float go2 = biasS[384+tid] + gS[384+tid];
      float ii = sigm_f(gi2), ff = sigm_f(gf2), gg = tanh_f(gg2), oo = sigm_f(go2);
      float cn = ff * cF[tid] + ii * gg;
      float hn = oo * tanh_f(cn);
      cF[tid] = cn; hF[tid] = hn;
      Hy[((size_t)row*BB + b)*256 + dir*128 + tid] = hn;
    }
    __syncthreads();
  }
}

// ---------------------------------------------------------------------------
// Answer pointer network (unchanged). 16 WGs, 256 threads, 2 steps.
// ---------------------------------------------------------------------------
__global__ __launch_bounds__(256) void ptr_net(
    const float* __restrict__ Hq,    // [48,16,256]
    const float* __restrict__ Hs,    // [256,16,256]
    const float* __restrict__ attp,  // [256,16,128]
    const float* __restrict__ WaaT,  // [128][128]
    const float* __restrict__ wbeta, // [128]
    const float* __restrict__ WahT,  // [256][128]
    const float* __restrict__ bah,
    const float* __restrict__ WacT,
    const float* __restrict__ bac,
    const float* __restrict__ WihT,  // [256][512]
    const float* __restrict__ WhhT,  // [128][512]
    const float* __restrict__ bptr,  // [512]
    float* __restrict__ out) {       // [2,256,16]
  int b = blockIdx.x;
  int tid = threadIdx.x;
  __shared__ float qp[256], h[128], c[128], haa[128], pe2[256], wv[256], part[1024];
  __shared__ float red[1];
  {
    float acc = 0.0f;
#pragma unroll 8
    for (int q = 0; q < QQ; ++q) acc += Hq[((size_t)q*BB + b)*256 + tid];
    qp[tid] = acc * (1.0f/48.0f);
  }
  __syncthreads();
  if (tid < 128) {
    float ah = bah[tid], ac = bac[tid];
#pragma unroll 8
    for (int k = 0; k < 256; ++k) {
      ah += qp[k] * WahT[k*128 + tid];
      ac += qp[k] * WacT[k*128 + tid];
    }
    h[tid] = ah; c[tid] = ac;
  }
  __syncthreads();
  for (int step = 0; step < 2; ++step) {
    if (tid < 128) {
      float acc = 0.0f;
#pragma unroll 8
      for (int k = 0; k < 128; ++k) acc += h[k] * WaaT[k*128 + tid];
      haa[tid] = acc;
    }
    __syncthreads();
    {
      const float* ap = attp + (size_t)tid*BB*128 + b*128;
      float s = 0.0f;
#pragma unroll 8
      for (int k = 0; k < 128; ++k) s += wbeta[k] * tanh_f(ap[k] + haa[k]);
      pe2[tid] = __expf(s);
    }
    __syncthreads();
    if (tid < 64) {
      float s2 = pe2[tid] + pe2[tid+64] + pe2[tid+128] + pe2[tid+192];
#pragma unroll
      for (int off = 32; off; off >>= 1) s2 += __shfl_down(s2, off);
      if (tid == 0) red[0] = s2;
    }
    __syncthreads();
    float inv = fast_rcp(red[0]);
    out[((size_t)step*PP + tid)*BB + b] = pe2[tid] * inv;
    {
      float acc = 0.0f;
#pragma unroll 8
      for (int p2 = 0; p2 < PP; ++p2) acc += pe2[p2] * Hs[((size_t)p2*BB + b)*256 + tid];
      wv[tid] = acc * inv;
    }
    __syncthreads();
    {
      int jq = tid & 127, kh = tid >> 7;
      float a0=0,a1=0,a2=0,a3=0;
      const float* wp = WihT + (size_t)kh*128*512 + jq*4;
      const float* vp = &wv[kh*128];
#pragma unroll 16
      for (int k = 0; k < 128; ++k) {
        float4 w4 = *(const float4*)&wp[(size_t)k*512];
        float v = vp[k];
        a0 += v*w4.x; a1 += v*w4.y; a2 += v*w4.z; a3 += v*w4.w;
      }
      const float* wp2 = WhhT + (size_t)kh*64*512 + jq*4;
      const float* hp = &h[kh*64];
#pragma unroll
      for (int k = 0; k < 64; ++k) {
        float4 w4 = *(const float4*)&wp2[(size_t)k*512];
        float v = hp[k];
        a0 += v*w4.x; a1 += v*w4.y; a2 += v*w4.z; a3 += v*w4.w;
      }
      part[kh*512 + jq*4 + 0] = a0; part[kh*512 + jq*4 + 1] = a1;
      part[kh*512 + jq*4 + 2] = a2; part[kh*512 + jq*4 + 3] = a3;
    }
    __syncthreads();
    if (tid < 128) {
      float gii = bptr[tid]     + part[tid]     + part[512+tid];
      float gff = bptr[128+tid] + part[128+tid] + part[640+tid];
      float ggg = bptr[256+tid] + part[256+tid] + part[768+tid];
      float goo = bptr[384+tid] + part[384+tid] + part[896+tid];
      float ii = sigm_f(gii), ff = sigm_f(gff), gg = tanh_f(ggg), oo = sigm_f(goo);
      float cn = ff * c[tid] + ii * gg;
      h[tid] = oo * tanh_f(cn); c[tid] = cn;
    }
    __syncthreads();
  }
}

// ---------------------------------------------------------------------------
extern "C" void kernel_launch(void* const* d_in, const int* in_sizes, int n_in,
                              void* d_out, int out_size, void* d_ws, size_t ws_size,
                              hipStream_t stream) {
  const float* p_inp  = (const float*)d_in[0];
  const float* q_inp  = (const float*)d_in[1];
  const float* g0_Wih = (const float*)d_in[2];
  const float* g0_Whh = (const float*)d_in[3];
  const float* g0_bih = (const float*)d_in[4];
  const float* g0_bhh = (const float*)d_in[5];
  const float* g1_Wih = (const float*)d_in[6];
  const float* g1_Whh = (const float*)d_in[7];
  const float* g1_bih = (const float*)d_in[8];
  const float* g1_bhh = (const float*)d_in[9];
  const float* g2_Wih = (const float*)d_in[10];
  const float* g2_Whh = (const float*)d_in[11];
  const float* g2_bih = (const float*)d_in[12];
  const float* g2_bhh = (const float*)d_in[13];
  const float* Wq     = (const float*)d_in[14];
  const float* Wp     = (const float*)d_in[15];
  const float* Wh     = (const float*)d_in[16];
  const float* w_alpha= (const float*)d_in[17];
  const float* Wg_m   = (const float*)d_in[18];
  const float* m_Wih  = (const float*)d_in[19];
  const float* m_Whh  = (const float*)d_in[20];
  const float* m_b    = (const float*)d_in[21];
  const float* Wsp    = (const float*)d_in[22];
  const float* Wsh    = (const float*)d_in[23];
  const float* w_gamma= (const float*)d_in[24];
  const float* Wg_s   = (const float*)d_in[25];
  const float* s_Wih  = (const float*)d_in[26];
  const float* s_Whh  = (const float*)d_in[27];
  const float* s_b    = (const float*)d_in[28];
  const float* Wal    = (const float*)d_in[29];
  const float* Waa    = (const float*)d_in[30];
  const float* w_beta = (const float*)d_in[31];
  const float* Wah    = (const float*)d_in[32];
  const float* bah    = (const float*)d_in[33];
  const float* Wac    = (const float*)d_in[34];
  const float* bac    = (const float*)d_in[35];
  const float* pt_Wih = (const float*)d_in[36];
  const float* pt_Whh = (const float*)d_in[37];
  const float* pt_b   = (const float*)d_in[38];

  float* ws = (float*)d_ws;
  size_t o = 0;
  auto alloc = [&](size_t n) { float* p = ws + o; o += n; return p; };
  // fp32 transposes (pointer net)
  float* WaaT   = alloc(16384);
  float* WahT   = alloc(32768);
  float* WacT   = alloc(32768);
  float* ptWihT = alloc(131072);
  float* ptWhhT = alloc(65536);
  // GRU fp16 k-major weights
  f16* g0WhhH = (f16*)alloc(24576);
  f16* g1WhhH = (f16*)alloc(24576);
  f16* g2WhhH = (f16*)alloc(24576);
  // attn packed h2 weights (size in floats == dword count)
  h2* mWihP  = (h2*)alloc(131072);  // [512][256]
  h2* mWgwP  = (h2*)alloc(65536);   // [512][128]
  h2* mWhhP  = (h2*)alloc(32768);   // [512][64]
  h2* mWhidP = (h2*)alloc(8192);    // [128][64]
  h2* sWihP  = (h2*)alloc(131072);
  h2* sWgwP  = (h2*)alloc(65536);
  h2* sWhhP  = (h2*)alloc(32768);
  h2* sWhidP = (h2*)alloc(8192);
  // persistent activations
  float* Hp  = alloc(1048576);   // [256,16,256]
  float* Hq_ = alloc(196608);    // [48,16,256]
  float* Hr  = alloc(1048576);
  float* Hs_ = alloc(1048576);
  // phase-reused region
  float* A = alloc(6225920);
  // GRU views
  float* gi_p = A;                 // [2,256,16,384] (layer0 uses [256,16,384])
  float* gi_q = A + 3145728;       // [2,48,16,384]
  float* hA_p = A + 3735552;       // [2,256,16,128]
  float* hB_p = A + 4784128;
  float* hA_q = A + 5832704;       // [2,48,16,128]
  float* hB_q = A + 6029312;       // [2,48,16,128]
  // match views
  float* attq  = A;                // [48,16,128] fp32
  float* Xp    = A + 98304;        // [256,16,128]
  float* XgM   = A + 622592;       // [256,16,512]
  f16*   attqH = (f16*)(A + 2719744);  // [16,48,128]
  f16*   HqH   = (f16*)(A + 2768896);  // [16,48,256]
  // self views
  float* attsp  = A;               // [256,16,128]
  float* XgS    = A + 524288;      // [256,16,512]
  f16*   attspH = (f16*)(A + 2621440); // [16,256,128]
  f16*   HrH    = (f16*)(A + 2883584); // [16,256,256]
  // pointer view
  float* attp = A;                 // [256,16,128]

  // 1. fp32 transposes (pointer net weights)
  TDescs tds;
  tds.d[0] = { Waa,    WaaT,   128, 128, 128, 0 };
  tds.d[1] = { Wah,    WahT,   128, 256, 256, 0 };
  tds.d[2] = { Wac,    WacT,   128, 256, 256, 0 };
  tds.d[3] = { pt_Wih, ptWihT, 512, 256, 256, 0 };
  tds.d[4] = { pt_Whh, ptWhhT, 512, 128, 128, 0 };
  transpose_many<<<dim3(512, 5), 256, 0, stream>>>(tds);

  // 2. GRU fp16 k-major converts
  GDescs gds;
  gds.d[0] = { g0_Whh, g0WhhH, 384, 128, 128 };
  gds.d[1] = { g1_Whh, g1WhhH, 384, 128, 128 };
  gds.d[2] = { g2_Whh, g2WhhH, 384, 128, 128 };
  conv_w16_many<<<dim3(192, 3), 256, 0, stream>>>(gds);

  // 3. attn weight row-pair packs (raw torch [j][k] layout, pairs along k)
  PDescs pds;
  pds.d[0] = { m_Wih, mWihP,  512, 512, 512, 0 };
  pds.d[1] = { Wg_m,  mWgwP,  512, 256, 512, 256 };
  pds.d[2] = { m_Whh, mWhhP,  512, 128, 128, 0 };
  pds.d[3] = { Wh,    mWhidP, 128, 128, 128, 0 };
  pds.d[4] = { s_Wih, sWihP,  512, 512, 512, 0 };
  pds.d[5] = { Wg_s,  sWgwP,  512, 256, 512, 256 };
  pds.d[6] = { s_Whh, sWhhP,  512, 128, 128, 0 };
  pds.d[7] = { Wsh,   sWhidP, 128, 128, 128, 0 };
  pack_pairs_many<<<dim3(512, 8), 256, 0, stream>>>(pds);

  // 4. GRU encoder
  gemm_nt<<<dim3(64, 6),  256, 0, stream>>>(p_inp, 556, g0_Wih, 556, g0_bih, gi_p, 384, 556);
  gemm_nt<<<dim3(12, 6),  256, 0, stream>>>(q_inp, 556, g0_Wih, 556, g0_bih, gi_q, 384, 556);
  gru_rec<<<16, 512, 0, stream>>>(gi_p, gi_q, g0WhhH, g0_bhh, hA_p, hA_q, nullptr, nullptr, 1, 0);
  gemm_nt<<<dim3(128, 6), 256, 0, stream>>>(hA_p, 128, g1_Wih, 128, g1_bih, gi_p, 384, 128);
  gemm_nt<<<dim3(24, 6),  256, 0, stream>>>(hA_q, 128, g1_Wih, 128, g1_bih, gi_q, 384, 128);
  gru_rec<<<16, 512, 0, stream>>>(gi_p, gi_q, g1WhhH, g1_bhh, hB_p, hB_q, nullptr, nullptr, 0, 0);
  gemm_nt<<<dim3(128, 6), 256, 0, stream>>>(hB_p, 128, g2_Wih, 128, g2_bih, gi_p, 384, 128);
  gemm_nt<<<dim3(24, 6),  256, 0, stream>>>(hB_q, 128, g2_Wih, 128, g2_bih, gi_q, 384, 128);
  gru_rec<<<16, 512, 0, stream>>>(gi_p, gi_q, g2WhhH, g2_bhh, hA_p, hA_q, Hp, Hq_, 0, 1);

  // 5. match-LSTM (passage attends over question)
  gemm_nt<<<dim3(12, 2), 256, 0, stream>>>(Hq_, 256, Wq, 256, nullptr, attq, 128, 256);
  gemm_nt<<<dim3(64, 2), 256, 0, stream>>>(Hp, 256, Wp, 256, nullptr, Xp, 128, 256);
  gemm_nt<<<dim3(64, 8), 256, 0, stream>>>(Hp, 256, Wg_m, 512, nullptr, XgM, 512, 256);
  conv_perm16<<<dim3(48, 16), 128, 0, stream>>>(attq, attqH, 128);
  conv_perm16<<<dim3(48, 16), 256, 0, stream>>>(Hq_, HqH, 256);
  attn_reg<48><<<32, 1024, 0, stream>>>(Hp, (const h2*)HqH, (const h2*)attqH, Xp, XgM,
                                        w_alpha, mWhidP, mWgwP, mWihP, mWhhP, m_b, Hr);

  // 6. self-matching (Wmem == Wcur == Wsp: one projection serves both)
  gemm_nt<<<dim3(64, 2), 256, 0, stream>>>(Hr, 256, Wsp, 256, nullptr, attsp, 128, 256);
  gemm_nt<<<dim3(64, 8), 256, 0, stream>>>(Hr, 256, Wg_s, 512, nullptr, XgS, 512, 256);
  conv_perm16<<<dim3(256, 16), 128, 0, stream>>>(attsp, attspH, 128);
  conv_perm16<<<dim3(256, 16), 256, 0, stream>>>(Hr, HrH, 256);
  attn_reg<256><<<32, 1024, 0, stream>>>(Hr, (const h2*)HrH, (const h2*)attspH, attsp, XgS,
                                         w_gamma, sWhidP, sWgwP, sWihP, sWhhP, s_b, Hs_);

  // 7. pointer network
  gemm_nt<<<dim3(64, 2), 256, 0, stream>>>(Hs_, 256, Wal, 256, nullptr, attp, 128, 256);
  ptr_net<<<16, 256, 0, stream>>>(Hq_, Hs_, attp, WaaT, w_beta, WahT, bah, WacT, bac,
                                  ptWihT, ptWhhT, pt_b, (float*)d_out);
}

// Round 7
// 13781.064 us; speedup vs baseline: 2.5004x; 2.5004x over previous
//
#include <hip/hip_runtime.h>

// ---------------------------------------------------------------------------
// R-Net forward on MI355X. Round 7: the clean fp16 A/B on the R2 structure.
// R2 (fp32, 512thr, LDS-partial stages, 8 barriers/step) = best known 17.45ms.
// This round changes ONLY the streamed operands: weights/attT/Hmem -> f16
// (k-major, f16x8 16B loads in the two big stages, 8 cols/thread), halving
// per-CU bytes/step (2.2 -> 1.05 MB) and load-instruction count. Topology,
// stage order, reductions, barriers: identical to R2.
//   P=256, Q=48, B=16, H=128, D=556, 2H=256, 3H=384, 4H=512
// ---------------------------------------------------------------------------

#define PP 256
#define QQ 48
#define BB 16

typedef _Float16 f16;
typedef f16 f16x4 __attribute__((ext_vector_type(4)));
typedef f16 f16x8 __attribute__((ext_vector_type(8)));

__device__ __forceinline__ float fast_rcp(float x) { return __builtin_amdgcn_rcpf(x); }
__device__ __forceinline__ float tanh_f(float x) {
  float e = __expf(2.0f * x);
  return 1.0f - 2.0f * fast_rcp(1.0f + e);
}
__device__ __forceinline__ float sigm_f(float x) {
  return fast_rcp(1.0f + __expf(-x));
}

// ---------------------------------------------------------------------------
// Generic C[M,N] = A[M,K] @ W[N,K]^T + bias.  64x64 tiles, BK=16, 256 thr.
// ---------------------------------------------------------------------------
__global__ __launch_bounds__(256) void gemm_nt(
    const float* __restrict__ A, int lda,
    const float* __restrict__ W, int ldw,
    const float* __restrict__ bias,
    float* __restrict__ C, int ldc, int K) {
  __shared__ float As[64][17];
  __shared__ float Ws[64][17];
  int tid = threadIdx.x;
  int m0 = blockIdx.x * 64, n0 = blockIdx.y * 64;
  int lr = tid >> 2, lq = (tid & 3) * 4;
  int tr = tid >> 4, tc = tid & 15;
  float acc[4][4] = {};
  for (int k0 = 0; k0 < K; k0 += 16) {
    float4 av = {0,0,0,0}, wv = {0,0,0,0};
    if (k0 + lq < K) {
      av = *(const float4*)&A[(size_t)(m0 + lr) * lda + k0 + lq];
      wv = *(const float4*)&W[(size_t)(n0 + lr) * ldw + k0 + lq];
    }
    __syncthreads();
    As[lr][lq+0] = av.x; As[lr][lq+1] = av.y; As[lr][lq+2] = av.z; As[lr][lq+3] = av.w;
    Ws[lr][lq+0] = wv.x; Ws[lr][lq+1] = wv.y; Ws[lr][lq+2] = wv.z; Ws[lr][lq+3] = wv.w;
    __syncthreads();
#pragma unroll
    for (int kk = 0; kk < 16; ++kk) {
      float a4[4], b4[4];
#pragma unroll
      for (int i = 0; i < 4; ++i) a4[i] = As[tr*4+i][kk];
#pragma unroll
      for (int j = 0; j < 4; ++j) b4[j] = Ws[tc*4+j][kk];
#pragma unroll
      for (int i = 0; i < 4; ++i)
#pragma unroll
        for (int j = 0; j < 4; ++j) acc[i][j] += a4[i] * b4[j];
    }
  }
#pragma unroll
  for (int i = 0; i < 4; ++i) {
    int m = m0 + tr*4 + i;
#pragma unroll
    for (int j = 0; j < 4; ++j) {
      int n = n0 + tc*4 + j;
      C[(size_t)m * ldc + n] = acc[i][j] + (bias ? bias[n] : 0.0f);
    }
  }
}

// ---------------------------------------------------------------------------
// Batched fp32 transposes (pointer-net weights)
// ---------------------------------------------------------------------------
struct TDesc { const float* src; float* dst; int R, C, ld, off; };
struct TDescs { TDesc d[5]; };

__global__ __launch_bounds__(256) void transpose_many(TDescs ds) {
  TDesc d = ds.d[blockIdx.y];
  int idx = blockIdx.x * 256 + threadIdx.x;
  if (idx < d.R * d.C) {
    int r = idx / d.C, cc = idx % d.C;
    d.dst[(size_t)cc * d.R + r] = d.src[(size_t)r * d.ld + d.off + cc];
  }
}

// ---------------------------------------------------------------------------
// Batched fp32->fp16 k-major converts: dst[k*R + j] = src[j*ld + off + k]
// ---------------------------------------------------------------------------
struct HDesc { const float* src; f16* dst; int R, C, ld, off; };
struct HDescs { HDesc d[11]; };

__global__ __launch_bounds__(256) void conv_w16_many(HDescs ds) {
  HDesc d = ds.d[blockIdx.y];
  int idx = blockIdx.x * 256 + threadIdx.x;
  if (idx < d.R * d.C) {
    int j = idx / d.C, k = idx % d.C;
    d.dst[(size_t)k * d.R + j] = (f16)d.src[(size_t)j * d.ld + d.off + k];
  }
}

// att fp32 [QM,16,128] -> f16 [16][128][QM]  (b-h-q layout for stage B)
__global__ __launch_bounds__(256) void conv_attT(
    const float* __restrict__ src, f16* __restrict__ dst, int QM) {
  int idx = blockIdx.x * 256 + threadIdx.x;
  if (idx < 16*128*QM) {
    int q = idx % QM, h = (idx / QM) & 127, b = idx / (QM*128);
    dst[idx] = (f16)src[((size_t)q*BB + b)*128 + h];
  }
}

// [T,16,D] fp32 -> [16,T,D] fp16  (grid = (T,16), block = D)
__global__ void conv_perm16(const float* __restrict__ src, f16* __restrict__ dst, int D) {
  int t = blockIdx.x, b = blockIdx.y, d = threadIdx.x;
  dst[((size_t)b*gridDim.x + t)*D + d] = (f16)src[((size_t)t*BB + b)*D + d];
}

// ---------------------------------------------------------------------------
// GRU recurrence, fp16 weights (R5 version, kept). 16 WGs, 512 threads.
// ---------------------------------------------------------------------------
__global__ __launch_bounds__(512) void gru_rec(
    const float* __restrict__ gi_p, const float* __restrict__ gi_q,
    const f16* __restrict__ WhhH,   // [128][384] k-major fp16
    const float* __restrict__ bhh,  // [384]
    float* __restrict__ out_p, float* __restrict__ out_q,
    float* __restrict__ Hp, float* __restrict__ Hq,
    int mode0, int finalmode) {
  int x = blockIdx.x;
  int seq = x >> 3, dir = (x >> 2) & 1, bg = x & 3;
  int T = seq ? QQ : PP;
  const float* gi = seq ? gi_q : gi_p;
  float* out = seq ? out_q : out_p;
  float* Hf  = seq ? Hq   : Hp;
  int b0 = bg * 4;
  int tid = threadIdx.x;
  __shared__ float hs[4][128];
  __shared__ float gpart[4][4][384];
  ((float*)hs)[tid] = 0.0f;
  __syncthreads();
  int ks = tid / 96;
  int jq = (tid % 96) * 4;
  int gb = tid >> 7, gj = tid & 127;
  for (int t = 0; t < T; ++t) {
    if (tid < 384) {
      float a[4][4] = {};
      const f16* wp = WhhH + (size_t)ks*32*384 + jq;
      const int kb = ks*32;
#pragma unroll 8
      for (int k = 0; k < 32; ++k) {
        f16x4 wv = *(const f16x4*)&wp[(size_t)k*384];
        float w0 = (float)wv[0], w1 = (float)wv[1], w2 = (float)wv[2], w3 = (float)wv[3];
#pragma unroll
        for (int bb = 0; bb < 4; ++bb) {
          float hv = hs[bb][kb + k];
          a[bb][0] += hv*w0; a[bb][1] += hv*w1; a[bb][2] += hv*w2; a[bb][3] += hv*w3;
        }
      }
#pragma unroll
      for (int bb = 0; bb < 4; ++bb) {
        gpart[ks][bb][jq+0]=a[bb][0]; gpart[ks][bb][jq+1]=a[bb][1];
        gpart[ks][bb][jq+2]=a[bb][2]; gpart[ks][bb][jq+3]=a[bb][3];
      }
    }
    __syncthreads();
    {
      size_t base;
      if (mode0) {
        int girow = dir ? (T-1-t) : t;
        base = ((size_t)girow*BB + b0+gb)*384;
      } else {
        base = (((size_t)dir*T + t)*BB + b0+gb)*384;
      }
      float ghr = bhh[gj]     + gpart[0][gb][gj]     + gpart[1][gb][gj]     + gpart[2][gb][gj]     + gpart[3][gb][gj];
      float ghz = bhh[128+gj] + gpart[0][gb][128+gj] + gpart[1][gb][128+gj] + gpart[2][gb][128+gj] + gpart[3][gb][128+gj];
      float ghn = bhh[256+gj] + gpart[0][gb][256+gj] + gpart[1][gb][256+gj] + gpart[2][gb][256+gj] + gpart[3][gb][256+gj];
      float gr = gi[base + gj], gz = gi[base + 128 + gj], gn = gi[base + 256 + gj];
      float r = sigm_f(gr + ghr);
      float z = sigm_f(gz + ghz);
      float n = tanh_f(gn + r * ghn);
      float h2v = (1.0f - z) * n + z * hs[gb][gj];
      hs[gb][gj] = h2v;
      if (finalmode) {
        int orow = dir ? (T-1-t) : t;
        Hf[((size_t)orow*BB + b0+gb)*256 + dir*128 + gj] = h2v;
      } else {
        out[(((size_t)dir*T + t)*BB + b0+gb)*128 + gj] = h2v;
      }
    }
    __syncthreads();
  }
}

// ---------------------------------------------------------------------------
// Gated additive-attention LSTM — R2 structure (512 thr, 32 WGs = {dir}x{b},
// LDS-partial stages, 8 barriers/step), streamed operands now f16.
// Stages E/G: 8 cols/thread, f16x8 16B loads, 8-way k-split.
// ---------------------------------------------------------------------------
template<int QM>
__global__ __launch_bounds__(512) void attn_rec(
    const float* __restrict__ Hseq,   // [256,16,256] fp32
    const f16*  __restrict__ HmemT,   // [16][QM][256] f16 per-b contiguous
    const f16*  __restrict__ attT,    // [16][128][QM] f16
    const float* __restrict__ Xcur,   // [256,16,128]
    const float* __restrict__ Xg,     // [256,16,512]
    const float* __restrict__ watt,   // [128]
    const f16*  __restrict__ WhidT,   // [128k][128j]
    const f16*  __restrict__ WgwT,    // [256k][512j]
    const f16*  __restrict__ WihT,    // [512k][512j]
    const f16*  __restrict__ WhhT,    // [128k][512j]
    const float* __restrict__ bias,   // [512]
    float* __restrict__ Hy) {         // [256,16,256]
  constexpr int QP  = (QM == QQ) ? 64 : 256;   // padded mem length (pow2)
  constexpr int HS  = 512 / QP;                // h-slices in score stage
  constexpr int hl  = 128 / HS;
  constexpr int hsh = (QM == QQ) ? 6 : 8;      // log2(QP)
  int dir = blockIdx.x >> 4, b = blockIdx.x & 15;
  int tid = threadIdx.x;
  __shared__ float h[128], c[128], xh[128], wa[128];
  __shared__ float pe[QP], zx[256], zg[512];
  __shared__ float pA[4][128];
  __shared__ float pB[512];
  __shared__ float pD[2][256];
  __shared__ float pE[8][512];
  __shared__ float pG[8][512];
  __shared__ float red[1];
  if (tid < 128) { h[tid] = 0.0f; c[tid] = 0.0f; wa[tid] = watt[tid]; }
  const f16* attb = attT  + (size_t)b*128*QM;
  const f16* memb = HmemT + (size_t)b*QM*256;
  __syncthreads();
  for (int t = 0; t < PP; ++t) {
    int row = dir ? (PP-1-t) : t;
    {  // Stage A: hW partials (4-way k-split) + xh / x_t loads
      int j = tid & 127, kh = tid >> 7;
      float acc = 0.0f;
      const f16* wp = WhidT + (size_t)kh*32*128 + j;
      const float* hp = &h[kh*32];
#pragma unroll
      for (int k = 0; k < 32; ++k) acc += (float)wp[(size_t)k*128] * hp[k];
      pA[kh][j] = acc;
      if (tid < 128) xh[tid] = Xcur[((size_t)row*BB + b)*128 + tid];
      else if (tid < 192) *(float4*)&zx[(tid-128)*4] =
          *(const float4*)&Hseq[((size_t)row*BB + b)*256 + (tid-128)*4];
    }
    __syncthreads();
    {  // Stage B: scores (fused xh combine), f16 attT
      int q = tid & (QP-1), hh = tid >> hsh;
      float acc = 0.0f;
      if (q < QM) {
        const f16* ap = attb + q;
        int h0 = hh * hl;
#pragma unroll 8
        for (int i = 0; i < hl; ++i) {
          int h2 = h0 + i;
          float xv = xh[h2] + pA[0][h2] + pA[1][h2] + pA[2][h2] + pA[3][h2];
          acc += wa[h2] * tanh_f((float)ap[(size_t)h2*QM] + xv);
        }
      }
      pB[hh*QP + q] = acc;
    }
    __syncthreads();
    if (tid < 64) {  // Stage C: combine score partials, exp, sum
      float lsum = 0.0f;
      for (int q2 = tid; q2 < QP; q2 += 64) {
        float s = 0.0f;
#pragma unroll
        for (int i = 0; i < HS; ++i) s += pB[i*QP + q2];
        float e = (q2 < QM) ? __expf(s) : 0.0f;
        pe[q2] = e; lsum += e;
      }
#pragma unroll
      for (int off = 32; off; off >>= 1) lsum += __shfl_down(lsum, off);
      if (tid == 0) red[0] = lsum;
    }
    __syncthreads();
    {  // Stage D: w numerator partials (2-way q-split), f16 Hmem per-b rows
      int d = tid & 255, qh = tid >> 8;
      int half = QM >> 1;
      float acc = 0.0f;
      const f16* mp = memb + (size_t)(qh*half)*256 + d;
      const float* pp = &pe[qh*half];
#pragma unroll 8
      for (int q2 = 0; q2 < half; ++q2)
        acc += pp[q2] * (float)mp[(size_t)q2*256];
      pD[qh][d] = acc;
    }
    __syncthreads();
    {  // Stage E: u = w @ WgwT (8-way k-split, 8 cols/thread, f16x8)
      int jo = tid & 63, kh = tid >> 6;
      float invred = fast_rcp(red[0]);
      float a[8] = {};
      const f16* wp = WgwT + (size_t)kh*32*512 + jo*8;
      int k0 = kh*32;
#pragma unroll 8
      for (int k = 0; k < 32; ++k) {
        float wk = (pD[0][k0+k] + pD[1][k0+k]) * invred;
        f16x8 wv = *(const f16x8*)&wp[(size_t)k*512];
#pragma unroll
        for (int cN = 0; cN < 8; ++cN) a[cN] += wk * (float)wv[cN];
      }
#pragma unroll
      for (int cN = 0; cN < 8; ++cN) pE[kh][jo*8 + cN] = a[cN];
    }
    __syncthreads();
    {  // Stage F: gated input zg = z * sigmoid(Xg + u); z = [x_t, w]
      float u = pE[0][tid] + pE[1][tid] + pE[2][tid] + pE[3][tid]
              + pE[4][tid] + pE[5][tid] + pE[6][tid] + pE[7][tid];
      float pre = Xg[((size_t)row*BB + b)*512 + tid] + u;
      float zval = (tid < 256) ? zx[tid]
                               : (pD[0][tid-256] + pD[1][tid-256]) * fast_rcp(red[0]);
      zg[tid] = zval * sigm_f(pre);
    }
    __syncthreads();
    {  // Stage G: gates = zg @ WihT + h @ WhhT (8-way k-split, 8 cols, f16x8)
      int jo = tid & 63, kh = tid >> 6;
      float a[8] = {};
      const f16* wp = WihT + (size_t)kh*64*512 + jo*8;
      const float* zp = &zg[kh*64];
#pragma unroll 8
      for (int k = 0; k < 64; ++k) {
        float zk = zp[k];
        f16x8 wv = *(const f16x8*)&wp[(size_t)k*512];
#pragma unroll
        for (int cN = 0; cN < 8; ++cN) a[cN] += zk * (float)wv[cN];
      }
      const f16* wp2 = WhhT + (size_t)kh*16*512 + jo*8;
      const float* hp = &h[kh*16];
#pragma unroll
      for (int k = 0; k < 16; ++k) {
        float hk = hp[k];
        f16x8 wv = *(const f16x8*)&wp2[(size_t)k*512];
#pragma unroll
        for (int cN = 0; cN < 8; ++cN) a[cN] += hk * (float)wv[cN];
      }
#pragma unroll
      for (int cN = 0; cN < 8; ++cN) pG[kh][jo*8 + cN] = a[cN];
    }
    __syncthreads();
    if (tid < 128) {  // Stage H: LSTM cell (gate order i,f,g,o)
      float gi2 = bias[tid], gf2 = bias[128+tid], gg2 = bias[256+tid], go2 = bias[384+tid];
#pragma unroll
      for (int s = 0; s < 8; ++s) {
        gi2 += pG[s][tid];       gf2 += pG[s][128+tid];
        gg2 += pG[s][256+tid];   go2 += pG[s][384+tid];
      }
      float ii = sigm_f(gi2), ff = sigm_f(gf2), gg = tanh_f(gg2), oo = sigm_f(go2);
      float cn = ff * c[tid] + ii * gg;
      float hn = oo * tanh_f(cn);
      c[tid] = cn; h[tid] = hn;
      Hy[((size_t)row*BB + b)*256 + dir*128 + tid] = hn;
    }
    __syncthreads();
  }
}

// ---------------------------------------------------------------------------
// Answer pointer network (unchanged). 16 WGs, 256 threads, 2 steps.
// ---------------------------------------------------------------------------
__global__ __launch_bounds__(256) void ptr_net(
    const float* __restrict__ Hq,    // [48,16,256]
    const float* __restrict__ Hs,    // [256,16,256]
    const float* __restrict__ attp,  // [256,16,128]
    const float* __restrict__ WaaT,  // [128][128]
    const float* __restrict__ wbeta, // [128]
    const float* __restrict__ WahT,  // [256][128]
    const float* __restrict__ bah,
    const float* __restrict__ WacT,
    const float* __restrict__ bac,
    const float* __restrict__ WihT,  // [256][512]
    const float* __restrict__ WhhT,  // [128][512]
    const float* __restrict__ bptr,  // [512]
    float* __restrict__ out) {       // [2,256,16]
  int b = blockIdx.x;
  int tid = threadIdx.x;
  __shared__ float qp[256], h[128], c[128], haa[128], pe2[256], wv[256], part[1024];
  __shared__ float red[1];
  {
    float acc = 0.0f;
#pragma unroll 8
    for (int q = 0; q < QQ; ++q) acc += Hq[((size_t)q*BB + b)*256 + tid];
    qp[tid] = acc * (1.0f/48.0f);
  }
  __syncthreads();
  if (tid < 128) {
    float ah = bah[tid], ac = bac[tid];
#pragma unroll 8
    for (int k = 0; k < 256; ++k) {
      ah += qp[k] * WahT[k*128 + tid];
      ac += qp[k] * WacT[k*128 + tid];
    }
    h[tid] = ah; c[tid] = ac;
  }
  __syncthreads();
  for (int step = 0; step < 2; ++step) {
    if (tid < 128) {
      float acc = 0.0f;
#pragma unroll 8
      for (int k = 0; k < 128; ++k) acc += h[k] * WaaT[k*128 + tid];
      haa[tid] = acc;
    }
    __syncthreads();
    {
      const float* ap = attp + (size_t)tid*BB*128 + b*128;
      float s = 0.0f;
#pragma unroll 8
      for (int k = 0; k < 128; ++k) s += wbeta[k] * tanh_f(ap[k] + haa[k]);
      pe2[tid] = __expf(s);
    }
    __syncthreads();
    if (tid < 64) {
      float s2 = pe2[tid] + pe2[tid+64] + pe2[tid+128] + pe2[tid+192];
#pragma unroll
      for (int off = 32; off; off >>= 1) s2 += __shfl_down(s2, off);
      if (tid == 0) red[0] = s2;
    }
    __syncthreads();
    float inv = fast_rcp(red[0]);
    out[((size_t)step*PP + tid)*BB + b] = pe2[tid] * inv;
    {
      float acc = 0.0f;
#pragma unroll 8
      for (int p2 = 0; p2 < PP; ++p2) acc += pe2[p2] * Hs[((size_t)p2*BB + b)*256 + tid];
      wv[tid] = acc * inv;
    }
    __syncthreads();
    {
      int jq = tid & 127, kh = tid >> 7;
      float a0=0,a1=0,a2=0,a3=0;
      const float* wp = WihT + (size_t)kh*128*512 + jq*4;
      const float* vp = &wv[kh*128];
#pragma unroll 16
      for (int k = 0; k < 128; ++k) {
        float4 w4 = *(const float4*)&wp[(size_t)k*512];
        float v = vp[k];
        a0 += v*w4.x; a1 += v*w4.y; a2 += v*w4.z; a3 += v*w4.w;
      }
      const float* wp2 = WhhT + (size_t)kh*64*512 + jq*4;
      const float* hp = &h[kh*64];
#pragma unroll
      for (int k = 0; k < 64; ++k) {
        float4 w4 = *(const float4*)&wp2[(size_t)k*512];
        float v = hp[k];
        a0 += v*w4.x; a1 += v*w4.y; a2 += v*w4.z; a3 += v*w4.w;
      }
      part[kh*512 + jq*4 + 0] = a0; part[kh*512 + jq*4 + 1] = a1;
      part[kh*512 + jq*4 + 2] = a2; part[kh*512 + jq*4 + 3] = a3;
    }
    __syncthreads();
    if (tid < 128) {
      float gii = bptr[tid]     + part[tid]     + part[512+tid];
      float gff = bptr[128+tid] + part[128+tid] + part[640+tid];
      float ggg = bptr[256+tid] + part[256+tid] + part[768+tid];
      float goo = bptr[384+tid] + part[384+tid] + part[896+tid];
      float ii = sigm_f(gii), ff = sigm_f(gff), gg = tanh_f(ggg), oo = sigm_f(goo);
      float cn = ff * c[tid] + ii * gg;
      h[tid] = oo * tanh_f(cn); c[tid] = cn;
    }
    __syncthreads();
  }
}

// ---------------------------------------------------------------------------
extern "C" void kernel_launch(void* const* d_in, const int* in_sizes, int n_in,
                              void* d_out, int out_size, void* d_ws, size_t ws_size,
                              hipStream_t stream) {
  const float* p_inp  = (const float*)d_in[0];
  const float* q_inp  = (const float*)d_in[1];
  const float* g0_Wih = (const float*)d_in[2];
  const float* g0_Whh = (const float*)d_in[3];
  const float* g0_bih = (const float*)d_in[4];
  const float* g0_bhh = (const float*)d_in[5];
  const float* g1_Wih = (const float*)d_in[6];
  const float* g1_Whh = (const float*)d_in[7];
  const float* g1_bih = (const float*)d_in[8];
  const float* g1_bhh = (const float*)d_in[9];
  const float* g2_Wih = (const float*)d_in[10];
  const float* g2_Whh = (const float*)d_in[11];
  const float* g2_bih = (const float*)d_in[12];
  const float* g2_bhh = (const float*)d_in[13];
  const float* Wq     = (const float*)d_in[14];
  const float* Wp     = (const float*)d_in[15];
  const float* Wh     = (const float*)d_in[16];
  const float* w_alpha= (const float*)d_in[17];
  const float* Wg_m   = (const float*)d_in[18];
  const float* m_Wih  = (const float*)d_in[19];
  const float* m_Whh  = (const float*)d_in[20];
  const float* m_b    = (const float*)d_in[21];
  const float* Wsp    = (const float*)d_in[22];
  const float* Wsh    = (const float*)d_in[23];
  const float* w_gamma= (const float*)d_in[24];
  const float* Wg_s   = (const float*)d_in[25];
  const float* s_Wih  = (const float*)d_in[26];
  const float* s_Whh  = (const float*)d_in[27];
  const float* s_b    = (const float*)d_in[28];
  const float* Wal    = (const float*)d_in[29];
  const float* Waa    = (const float*)d_in[30];
  const float* w_beta = (const float*)d_in[31];
  const float* Wah    = (const float*)d_in[32];
  const float* bah    = (const float*)d_in[33];
  const float* Wac    = (const float*)d_in[34];
  const float* bac    = (const float*)d_in[35];
  const float* pt_Wih = (const float*)d_in[36];
  const float* pt_Whh = (const float*)d_in[37];
  const float* pt_b   = (const float*)d_in[38];

  float* ws = (float*)d_ws;
  size_t o = 0;
  auto alloc = [&](size_t n) { float* p = ws + o; o += n; return p; };
  // fp32 transposes (pointer net)
  float* WaaT   = alloc(16384);
  float* WahT   = alloc(32768);
  float* WacT   = alloc(32768);
  float* ptWihT = alloc(131072);
  float* ptWhhT = alloc(65536);
  // f16 k-major recurrent weights (alloc counts are floats = halves/2)
  f16* g0WhhH = (f16*)alloc(24576);
  f16* g1WhhH = (f16*)alloc(24576);
  f16* g2WhhH = (f16*)alloc(24576);
  f16* mWihT  = (f16*)alloc(131072);  // [512k][512j]
  f16* mWgwT  = (f16*)alloc(65536);   // [256k][512j]
  f16* mWhhT  = (f16*)alloc(32768);   // [128k][512j]
  f16* mWhidT = (f16*)alloc(8192);    // [128k][128j]
  f16* sWihT  = (f16*)alloc(131072);
  f16* sWgwT  = (f16*)alloc(65536);
  f16* sWhhT  = (f16*)alloc(32768);
  f16* sWhidT = (f16*)alloc(8192);
  // persistent activations
  float* Hp  = alloc(1048576);   // [256,16,256]
  float* Hq_ = alloc(196608);    // [48,16,256]
  float* Hr  = alloc(1048576);
  float* Hs_ = alloc(1048576);
  // phase-reused region
  float* A = alloc(6225920);
  // GRU views
  float* gi_p = A;                 // [2,256,16,384] (layer0 uses [256,16,384])
  float* gi_q = A + 3145728;       // [2,48,16,384]
  float* hA_p = A + 3735552;       // [2,256,16,128]
  float* hB_p = A + 4784128;
  float* hA_q = A + 5832704;       // [2,48,16,128]
  float* hB_q = A + 6029312;       // ends 6225920
  // match views
  float* attq   = A;               // [48,16,128] fp32
  float* Xp     = A + 98304;       // [256,16,128]
  float* XgM    = A + 622592;      // [256,16,512] ends 2719744
  f16*   attqTH = (f16*)(A + 2818048);  // [16,128,48]  (49152 floats)
  f16*   HqTH   = (f16*)(A + 2867200);  // [16,48,256]  (98304 floats)
  // self views
  float* attsp   = A;              // [256,16,128]
  float* XgS     = A + 1048576;    // [256,16,512] ends 3145728
  f16*   attspTH = (f16*)(A + 3145728); // [16,128,256] (262144 floats)
  f16*   HrTH    = (f16*)(A + 3407872); // [16,256,256] (524288 floats)
  // pointer view
  float* attp = A;                 // [256,16,128]

  // 1. fp32 transposes (pointer net weights)
  TDescs tds;
  tds.d[0] = { Waa,    WaaT,   128, 128, 128, 0 };
  tds.d[1] = { Wah,    WahT,   128, 256, 256, 0 };
  tds.d[2] = { Wac,    WacT,   128, 256, 256, 0 };
  tds.d[3] = { pt_Wih, ptWihT, 512, 256, 256, 0 };
  tds.d[4] = { pt_Whh, ptWhhT, 512, 128, 128, 0 };
  transpose_many<<<dim3(512, 5), 256, 0, stream>>>(tds);

  // 2. f16 k-major weight converts
  HDescs hds;
  hds.d[0]  = { g0_Whh, g0WhhH, 384, 128, 128, 0 };
  hds.d[1]  = { g1_Whh, g1WhhH, 384, 128, 128, 0 };
  hds.d[2]  = { g2_Whh, g2WhhH, 384, 128, 128, 0 };
  hds.d[3]  = { m_Wih,  mWihT,  512, 512, 512, 0 };
  hds.d[4]  = { Wg_m,   mWgwT,  512, 256, 512, 256 };
  hds.d[5]  = { m_Whh,  mWhhT,  512, 128, 128, 0 };
  hds.d[6]  = { Wh,     mWhidT, 128, 128, 128, 0 };
  hds.d[7]  = { s_Wih,  sWihT,  512, 512, 512, 0 };
  hds.d[8]  = { Wg_s,   sWgwT,  512, 256, 512, 256 };
  hds.d[9]  = { s_Whh,  sWhhT,  512, 128, 128, 0 };
  hds.d[10] = { Wsh,    sWhidT, 128, 128, 128, 0 };
  conv_w16_many<<<dim3(1024, 11), 256, 0, stream>>>(hds);

  // 3. GRU encoder
  gemm_nt<<<dim3(64, 6),  256, 0, stream>>>(p_inp, 556, g0_Wih, 556, g0_bih, gi_p, 384, 556);
  gemm_nt<<<dim3(12, 6),  256, 0, stream>>>(q_inp, 556, g0_Wih, 556, g0_bih, gi_q, 384, 556);
  gru_rec<<<16, 512, 0, stream>>>(gi_p, gi_q, g0WhhH, g0_bhh, hA_p, hA_q, nullptr, nullptr, 1, 0);
  gemm_nt<<<dim3(128, 6), 256, 0, stream>>>(hA_p, 128, g1_Wih, 128, g1_bih, gi_p, 384, 128);
  gemm_nt<<<dim3(24, 6),  256, 0, stream>>>(hA_q, 128, g1_Wih, 128, g1_bih, gi_q, 384, 128);
  gru_rec<<<16, 512, 0, stream>>>(gi_p, gi_q, g1WhhH, g1_bhh, hB_p, hB_q, nullptr, nullptr, 0, 0);
  gemm_nt<<<dim3(128, 6), 256, 0, stream>>>(hB_p, 128, g2_Wih, 128, g2_bih, gi_p, 384, 128);
  gemm_nt<<<dim3(24, 6),  256, 0, stream>>>(hB_q, 128, g2_Wih, 128, g2_bih, gi_q, 384, 128);
  gru_rec<<<16, 512, 0, stream>>>(gi_p, gi_q, g2WhhH, g2_bhh, hA_p, hA_q, Hp, Hq_, 0, 1);

  // 4. match-LSTM (passage attends over question)
  gemm_nt<<<dim3(12, 2), 256, 0, stream>>>(Hq_, 256, Wq, 256, nullptr, attq, 128, 256);
  gemm_nt<<<dim3(64, 2), 256, 0, stream>>>(Hp, 256, Wp, 256, nullptr, Xp, 128, 256);
  gemm_nt<<<dim3(64, 8), 256, 0, stream>>>(Hp, 256, Wg_m, 512, nullptr, XgM, 512, 256);
  conv_attT<<<dim3(384), 256, 0, stream>>>(attq, attqTH, 48);
  conv_perm16<<<dim3(48, 16), 256, 0, stream>>>(Hq_, HqTH, 256);
  attn_rec<QQ><<<32, 512, 0, stream>>>(Hp, HqTH, attqTH, Xp, XgM, w_alpha,
                                       mWhidT, mWgwT, mWihT, mWhhT, m_b, Hr);

  // 5. self-matching (Wmem == Wcur == Wsp: one projection serves both)
  gemm_nt<<<dim3(64, 2), 256, 0, stream>>>(Hr, 256, Wsp, 256, nullptr, attsp, 128, 256);
  gemm_nt<<<dim3(64, 8), 256, 0, stream>>>(Hr, 256, Wg_s, 512, nullptr, XgS, 512, 256);
  conv_attT<<<dim3(2048), 256, 0, stream>>>(attsp, attspTH, 256);
  conv_perm16<<<dim3(256, 16), 256, 0, stream>>>(Hr, HrTH, 256);
  attn_rec<PP><<<32, 512, 0, stream>>>(Hr, HrTH, attspTH, attsp, XgS, w_gamma,
                                       sWhidT, sWgwT, sWihT, sWhhT, s_b, Hs_);

  // 6. pointer network
  gemm_nt<<<dim3(64, 2), 256, 0, stream>>>(Hs_, 256, Wal, 256, nullptr, attp, 128, 256);
  ptr_net<<<16, 256, 0, stream>>>(Hq_, Hs_, attp, WaaT, w_beta, WahT, bah, WacT, bac,
                                  ptWihT, ptWhhT, pt_b, (float*)d_out);
}

// Round 8
// 9311.604 us; speedup vs baseline: 3.7006x; 1.4800x over previous
//
#include <hip/hip_runtime.h>

// ---------------------------------------------------------------------------
// R-Net forward on MI355X. Round 8: algebraic U-precompute + dot2 + LDS-host.
//  - u = w@Wgw^T == (sum_q pe*U[q])/den with U = Hmem@Wgw^T precomputed GEMM:
//    kills the per-step Wgw stream; stages D+E merge (8 -> 7 barriers).
//  - match phase (QM=48): HmemU (74KB) + attT (12KB) LDS-resident; per-step
//    global stream drops to Wih+Whh = 640KB.
//  - stage G uses v_dot2_f32_f16 on pair-packed Wih + h2-packed zg (validated
//    rounding, R6): VALU per element halved.
// Topology unchanged from R7: 32 WGs = {dir}x{b}, 512 threads, LDS partials.
//   P=256, Q=48, B=16, H=128, D=556, 2H=256, 3H=384, 4H=512
// ---------------------------------------------------------------------------

#define PP 256
#define QQ 48
#define BB 16

typedef _Float16 f16;
typedef f16 f16x4 __attribute__((ext_vector_type(4)));
typedef f16 f16x8 __attribute__((ext_vector_type(8)));
typedef f16 h2 __attribute__((ext_vector_type(2)));

__device__ __forceinline__ float fast_rcp(float x) { return __builtin_amdgcn_rcpf(x); }
__device__ __forceinline__ float tanh_f(float x) {
  float e = __expf(2.0f * x);
  return 1.0f - 2.0f * fast_rcp(1.0f + e);
}
__device__ __forceinline__ float sigm_f(float x) {
  return fast_rcp(1.0f + __expf(-x));
}
__device__ __forceinline__ float fdot2(h2 a, h2 b, float c) {
#if defined(__has_builtin)
#if __has_builtin(__builtin_amdgcn_fdot2)
  return __builtin_amdgcn_fdot2(a, b, c, false);
#else
  return c + (float)a.x*(float)b.x + (float)a.y*(float)b.y;
#endif
#else
  return c + (float)a.x*(float)b.x + (float)a.y*(float)b.y;
#endif
}

// ---------------------------------------------------------------------------
// Generic C[M,N] = A[M,K] @ W[N,K]^T + bias.  64x64 tiles, BK=16, 256 thr.
// ---------------------------------------------------------------------------
__global__ __launch_bounds__(256) void gemm_nt(
    const float* __restrict__ A, int lda,
    const float* __restrict__ W, int ldw,
    const float* __restrict__ bias,
    float* __restrict__ C, int ldc, int K) {
  __shared__ float As[64][17];
  __shared__ float Ws[64][17];
  int tid = threadIdx.x;
  int m0 = blockIdx.x * 64, n0 = blockIdx.y * 64;
  int lr = tid >> 2, lq = (tid & 3) * 4;
  int tr = tid >> 4, tc = tid & 15;
  float acc[4][4] = {};
  for (int k0 = 0; k0 < K; k0 += 16) {
    float4 av = {0,0,0,0}, wv = {0,0,0,0};
    if (k0 + lq < K) {
      av = *(const float4*)&A[(size_t)(m0 + lr) * lda + k0 + lq];
      wv = *(const float4*)&W[(size_t)(n0 + lr) * ldw + k0 + lq];
    }
    __syncthreads();
    As[lr][lq+0] = av.x; As[lr][lq+1] = av.y; As[lr][lq+2] = av.z; As[lr][lq+3] = av.w;
    Ws[lr][lq+0] = wv.x; Ws[lr][lq+1] = wv.y; Ws[lr][lq+2] = wv.z; Ws[lr][lq+3] = wv.w;
    __syncthreads();
#pragma unroll
    for (int kk = 0; kk < 16; ++kk) {
      float a4[4], b4[4];
#pragma unroll
      for (int i = 0; i < 4; ++i) a4[i] = As[tr*4+i][kk];
#pragma unroll
      for (int j = 0; j < 4; ++j) b4[j] = Ws[tc*4+j][kk];
#pragma unroll
      for (int i = 0; i < 4; ++i)
#pragma unroll
        for (int j = 0; j < 4; ++j) acc[i][j] += a4[i] * b4[j];
    }
  }
#pragma unroll
  for (int i = 0; i < 4; ++i) {
    int m = m0 + tr*4 + i;
#pragma unroll
    for (int j = 0; j < 4; ++j) {
      int n = n0 + tc*4 + j;
      C[(size_t)m * ldc + n] = acc[i][j] + (bias ? bias[n] : 0.0f);
    }
  }
}

// ---------------------------------------------------------------------------
// U GEMM writing f16 into the combined HmemU array:
// rows m = q*16+b of A; dst[(b*QM + q)*768 + 256 + n] = (f16)C[m][n]. N=512.
// ---------------------------------------------------------------------------
__global__ __launch_bounds__(256) void gemm_f16u(
    const float* __restrict__ A, int lda,
    const float* __restrict__ W, int ldw,
    f16* __restrict__ dst, int QMd, int K) {
  __shared__ float As[64][17];
  __shared__ float Ws[64][17];
  int tid = threadIdx.x;
  int m0 = blockIdx.x * 64, n0 = blockIdx.y * 64;
  int lr = tid >> 2, lq = (tid & 3) * 4;
  int tr = tid >> 4, tc = tid & 15;
  float acc[4][4] = {};
  for (int k0 = 0; k0 < K; k0 += 16) {
    float4 av = *(const float4*)&A[(size_t)(m0 + lr) * lda + k0 + lq];
    float4 wv = *(const float4*)&W[(size_t)(n0 + lr) * ldw + k0 + lq];
    __syncthreads();
    As[lr][lq+0] = av.x; As[lr][lq+1] = av.y; As[lr][lq+2] = av.z; As[lr][lq+3] = av.w;
    Ws[lr][lq+0] = wv.x; Ws[lr][lq+1] = wv.y; Ws[lr][lq+2] = wv.z; Ws[lr][lq+3] = wv.w;
    __syncthreads();
#pragma unroll
    for (int kk = 0; kk < 16; ++kk) {
      float a4[4], b4[4];
#pragma unroll
      for (int i = 0; i < 4; ++i) a4[i] = As[tr*4+i][kk];
#pragma unroll
      for (int j = 0; j < 4; ++j) b4[j] = Ws[tc*4+j][kk];
#pragma unroll
      for (int i = 0; i < 4; ++i)
#pragma unroll
        for (int j = 0; j < 4; ++j) acc[i][j] += a4[i] * b4[j];
    }
  }
#pragma unroll
  for (int i = 0; i < 4; ++i) {
    int m = m0 + tr*4 + i;
    int q = m >> 4, bb = m & 15;
#pragma unroll
    for (int j = 0; j < 4; ++j) {
      int n = n0 + tc*4 + j;
      dst[((size_t)bb*QMd + q)*768 + 256 + n] = (f16)acc[i][j];
    }
  }
}

// Hmem fp32 [QM,16,256] -> f16 cols 0:256 of HmemU [16][QM][768]
__global__ void conv_hmemU(const float* __restrict__ src, f16* __restrict__ dst, int QM) {
  int q = blockIdx.x, b = blockIdx.y, d = threadIdx.x;
  dst[((size_t)b*QM + q)*768 + d] = (f16)src[((size_t)q*BB + b)*256 + d];
}

// ---------------------------------------------------------------------------
// Batched fp32 transposes (pointer-net weights)
// ---------------------------------------------------------------------------
struct TDesc { const float* src; float* dst; int R, C, ld, off; };
struct TDescs { TDesc d[5]; };

__global__ __launch_bounds__(256) void transpose_many(TDescs ds) {
  TDesc d = ds.d[blockIdx.y];
  int idx = blockIdx.x * 256 + threadIdx.x;
  if (idx < d.R * d.C) {
    int r = idx / d.C, cc = idx % d.C;
    d.dst[(size_t)cc * d.R + r] = d.src[(size_t)r * d.ld + d.off + cc];
  }
}

// ---------------------------------------------------------------------------
// Batched fp32->fp16 k-major converts: dst[k*R + j] = src[j*ld + k]
// ---------------------------------------------------------------------------
struct HDesc { const float* src; f16* dst; int R, C, ld; };
struct HDescs { HDesc d[7]; };

__global__ __launch_bounds__(256) void conv_w16_many(HDescs ds) {
  HDesc d = ds.d[blockIdx.y];
  int idx = blockIdx.x * 256 + threadIdx.x;
  if (idx < d.R * d.C) {
    int j = idx / d.C, k = idx % d.C;
    d.dst[(size_t)k * d.R + j] = (f16)d.src[(size_t)j * d.ld + k];
  }
}

// ---------------------------------------------------------------------------
// k-pair packs for dot2: dst[kp*J + j] = h2(src[j*ld + 2kp], src[j*ld + 2kp+1])
// ---------------------------------------------------------------------------
struct QDesc { const float* src; h2* dst; int J, K, ld; };
struct QDescs { QDesc d[2]; };

__global__ __launch_bounds__(256) void pack_pairs_many(QDescs ds) {
  QDesc d = ds.d[blockIdx.y];
  int KP = d.K >> 1;
  int idx = blockIdx.x * 256 + threadIdx.x;
  if (idx < KP * d.J) {
    int kp = idx / d.J, j = idx % d.J;
    h2 v;
    v.x = (f16)d.src[(size_t)j*d.ld + 2*kp];
    v.y = (f16)d.src[(size_t)j*d.ld + 2*kp + 1];
    d.dst[(size_t)kp*d.J + j] = v;
  }
}

// att fp32 [QM,16,128] -> f16 [16][128][QM]
__global__ __launch_bounds__(256) void conv_attT(
    const float* __restrict__ src, f16* __restrict__ dst, int QM) {
  int idx = blockIdx.x * 256 + threadIdx.x;
  if (idx < 16*128*QM) {
    int q = idx % QM, h = (idx / QM) & 127, b = idx / (QM*128);
    dst[idx] = (f16)src[((size_t)q*BB + b)*128 + h];
  }
}

// ---------------------------------------------------------------------------
// GRU recurrence, fp16 weights (R5 version, kept). 16 WGs, 512 threads.
// ---------------------------------------------------------------------------
__global__ __launch_bounds__(512) void gru_rec(
    const float* __restrict__ gi_p, const float* __restrict__ gi_q,
    const f16* __restrict__ WhhH,   // [128][384] k-major fp16
    const float* __restrict__ bhh,  // [384]
    float* __restrict__ out_p, float* __restrict__ out_q,
    float* __restrict__ Hp, float* __restrict__ Hq,
    int mode0, int finalmode) {
  int x = blockIdx.x;
  int seq = x >> 3, dir = (x >> 2) & 1, bg = x & 3;
  int T = seq ? QQ : PP;
  const float* gi = seq ? gi_q : gi_p;
  float* out = seq ? out_q : out_p;
  float* Hf  = seq ? Hq   : Hp;
  int b0 = bg * 4;
  int tid = threadIdx.x;
  __shared__ float hs[4][128];
  __shared__ float gpart[4][4][384];
  ((float*)hs)[tid] = 0.0f;
  __syncthreads();
  int ks = tid / 96;
  int jq = (tid % 96) * 4;
  int gb = tid >> 7, gj = tid & 127;
  for (int t = 0; t < T; ++t) {
    if (tid < 384) {
      float a[4][4] = {};
      const f16* wp = WhhH + (size_t)ks*32*384 + jq;
      const int kb = ks*32;
#pragma unroll 8
      for (int k = 0; k < 32; ++k) {
        f16x4 wv = *(const f16x4*)&wp[(size_t)k*384];
        float w0 = (float)wv[0], w1 = (float)wv[1], w2 = (float)wv[2], w3 = (float)wv[3];
#pragma unroll
        for (int bb = 0; bb < 4; ++bb) {
          float hv = hs[bb][kb + k];
          a[bb][0] += hv*w0; a[bb][1] += hv*w1; a[bb][2] += hv*w2; a[bb][3] += hv*w3;
        }
      }
#pragma unroll
      for (int bb = 0; bb < 4; ++bb) {
        gpart[ks][bb][jq+0]=a[bb][0]; gpart[ks][bb][jq+1]=a[bb][1];
        gpart[ks][bb][jq+2]=a[bb][2]; gpart[ks][bb][jq+3]=a[bb][3];
      }
    }
    __syncthreads();
    {
      size_t base;
      if (mode0) {
        int girow = dir ? (T-1-t) : t;
        base = ((size_t)girow*BB + b0+gb)*384;
      } else {
        base = (((size_t)dir*T + t)*BB + b0+gb)*384;
      }
      float ghr = bhh[gj]     + gpart[0][gb][gj]     + gpart[1][gb][gj]     + gpart[2][gb][gj]     + gpart[3][gb][gj];
      float ghz = bhh[128+gj] + gpart[0][gb][128+gj] + gpart[1][gb][128+gj] + gpart[2][gb][128+gj] + gpart[3][gb][128+gj];
      float ghn = bhh[256+gj] + gpart[0][gb][256+gj] + gpart[1][gb][256+gj] + gpart[2][gb][256+gj] + gpart[3][gb][256+gj];
      float gr = gi[base + gj], gz = gi[base + 128 + gj], gn = gi[base + 256 + gj];
      float r = sigm_f(gr + ghr);
      float z = sigm_f(gz + ghz);
      float n = tanh_f(gn + r * ghn);
      float h2v = (1.0f - z) * n + z * hs[gb][gj];
      hs[gb][gj] = h2v;
      if (finalmode) {
        int orow = dir ? (T-1-t) : t;
        Hf[((size_t)orow*BB + b0+gb)*256 + dir*128 + gj] = h2v;
      } else {
        out[(((size_t)dir*T + t)*BB + b0+gb)*128 + gj] = h2v;
      }
    }
    __syncthreads();
  }
}

// ---------------------------------------------------------------------------
// Gated additive-attention LSTM, round 8. 32 WGs = {dir}x{b}, 512 threads.
// 7 barriers/step. QM=48: HmemU+attT LDS-resident. dot2 on Wih.
// ---------------------------------------------------------------------------
template<int QM>
__global__ __launch_bounds__(512) void attn_rec2(
    const float* __restrict__ Hseq,   // [256,16,256] fp32
    const f16*  __restrict__ HmemU,   // [16][QM][768] f16 ([Hmem | U])
    const f16*  __restrict__ attT,    // [16][128][QM] f16
    const float* __restrict__ Xcur,   // [256,16,128]
    const float* __restrict__ Xg,     // [256,16,512]
    const float* __restrict__ watt,   // [128]
    const f16*  __restrict__ WhidT,   // [128k][128j]
    const h2*   __restrict__ WihP2,   // [256kp][512j] pair-packed
    const f16*  __restrict__ WhhT,    // [128k][512j]
    const float* __restrict__ bias,   // [512]
    float* __restrict__ Hy) {         // [256,16,256]
  constexpr bool HOST = (QM == QQ);
  constexpr int QP  = HOST ? 64 : 256;   // padded mem length (pow2)
  constexpr int HS  = 512 / QP;          // h-slices in score stage
  constexpr int hl  = 128 / HS;
  constexpr int hsh = HOST ? 6 : 8;      // log2(QP)
  constexpr int QR  = QM / 4;            // q rows per split in stage DE
  int dir = blockIdx.x >> 4, b = blockIdx.x & 15;
  int tid = threadIdx.x;
  __shared__ f16 attSL[HOST ? 128*QQ : 1];
  __shared__ f16 humSL[HOST ? QQ*768 : 1];
  __shared__ float h[128], c[128], xh[128], wa[128];
  __shared__ float peS[QP], zx[256];
  __shared__ h2 zgP[256];
  __shared__ float pA[4][128];
  __shared__ float pB[512];
  __shared__ float pDE[4][768];
  __shared__ float pG[8][512];
  __shared__ float biasS[512];
  __shared__ float red[1];
  if (tid < 128) { h[tid] = 0.0f; c[tid] = 0.0f; wa[tid] = watt[tid]; }
  biasS[tid] = bias[tid];
  const f16* attb = attT  + (size_t)b*128*QM;
  const f16* humb = HmemU + (size_t)b*QM*768;
  if constexpr (HOST) {   // one-time LDS residency
    for (int i = tid; i < QQ*768/8; i += 512)
      *(f16x8*)&humSL[i*8] = *(const f16x8*)&humb[(size_t)i*8];
    for (int i = tid; i < 128*QQ/8; i += 512)
      *(f16x8*)&attSL[i*8] = *(const f16x8*)&attb[(size_t)i*8];
  }
  __syncthreads();
  for (int t = 0; t < PP; ++t) {
    int row = dir ? (PP-1-t) : t;
    {  // Stage A: hW partials (4-way k-split) + xh / x_t loads
      int j = tid & 127, kh = tid >> 7;
      float acc = 0.0f;
      const f16* wp = WhidT + (size_t)kh*32*128 + j;
      const float* hp = &h[kh*32];
#pragma unroll
      for (int k = 0; k < 32; ++k) acc += (float)wp[(size_t)k*128] * hp[k];
      pA[kh][j] = acc;
      if (tid < 128) xh[tid] = Xcur[((size_t)row*BB + b)*128 + tid];
      else if (tid < 192) *(float4*)&zx[(tid-128)*4] =
          *(const float4*)&Hseq[((size_t)row*BB + b)*256 + (tid-128)*4];
    }
    __syncthreads();
    {  // Stage B: scores (fused xh combine)
      int q = tid & (QP-1), hh = tid >> hsh;
      float acc = 0.0f;
      if (q < QM) {
        const f16* ap = (HOST ? attSL : attb) + q;
        int h0 = hh * hl;
#pragma unroll 8
        for (int i = 0; i < hl; ++i) {
          int h2i = h0 + i;
          float xv = xh[h2i] + pA[0][h2i] + pA[1][h2i] + pA[2][h2i] + pA[3][h2i];
          acc += wa[h2i] * tanh_f((float)ap[(size_t)h2i*QM] + xv);
        }
      }
      pB[hh*QP + q] = acc;
    }
    __syncthreads();
    if (tid < 64) {  // Stage C: combine score partials, exp, sum
      float lsum = 0.0f;
      for (int q2 = tid; q2 < QP; q2 += 64) {
        float s = 0.0f;
#pragma unroll
        for (int i = 0; i < HS; ++i) s += pB[i*QP + q2];
        float e = (q2 < QM) ? __expf(s) : 0.0f;
        peS[q2] = e; lsum += e;
      }
#pragma unroll
      for (int off = 32; off; off >>= 1) lsum += __shfl_down(lsum, off);
      if (tid == 0) red[0] = lsum;
    }
    __syncthreads();
    {  // Stage DE (merged): [w | u_num] = sum_q pe[q] * HmemU[q][0:768]
      int oc = tid & 127, qs = tid >> 7;
      if (oc < 96) {
        float a[8] = {};
        if constexpr (HOST) {
          const f16* hp = &humSL[(size_t)(qs*QR)*768 + oc*8];
#pragma unroll
          for (int i = 0; i < QR; ++i) {
            float pv = peS[qs*QR + i];
            f16x8 mv = *(const f16x8*)&hp[(size_t)i*768];
#pragma unroll
            for (int cN = 0; cN < 8; ++cN) a[cN] += pv * (float)mv[cN];
          }
        } else {
          const f16* hp = humb + (size_t)(qs*QR)*768 + oc*8;
#pragma unroll 16
          for (int i = 0; i < QR; ++i) {
            float pv = peS[qs*QR + i];
            f16x8 mv = *(const f16x8*)&hp[(size_t)i*768];
#pragma unroll
            for (int cN = 0; cN < 8; ++cN) a[cN] += pv * (float)mv[cN];
          }
        }
#pragma unroll
        for (int cN = 0; cN < 8; ++cN) pDE[qs][oc*8 + cN] = a[cN];
      }
    }
    __syncthreads();
    if (tid < 256) {  // Stage F: zg pair = z * sigmoid(Xg + u), packed h2
      float invd = fast_rcp(red[0]);
      int j0 = 2*tid;
      float u0 = (pDE[0][256+j0] + pDE[1][256+j0] + pDE[2][256+j0] + pDE[3][256+j0]) * invd;
      float u1 = (pDE[0][257+j0] + pDE[1][257+j0] + pDE[2][257+j0] + pDE[3][257+j0]) * invd;
      float z0, z1;
      if (tid < 128) { z0 = zx[j0]; z1 = zx[j0+1]; }
      else {
        int d0 = j0 - 256;
        z0 = (pDE[0][d0]   + pDE[1][d0]   + pDE[2][d0]   + pDE[3][d0])   * invd;
        z1 = (pDE[0][d0+1] + pDE[1][d0+1] + pDE[2][d0+1] + pDE[3][d0+1]) * invd;
      }
      float2 xg2 = *(const float2*)&Xg[((size_t)row*BB + b)*512 + j0];
      h2 p;
      p.x = (f16)(z0 * sigm_f(xg2.x + u0));
      p.y = (f16)(z1 * sigm_f(xg2.y + u1));
      zgP[tid] = p;
    }
    __syncthreads();
    {  // Stage G: gates = zg @ Wih^T (dot2, pair-packed) + h @ Whh^T (cvt)
      int jo = tid & 63, kh = tid >> 6;
      float a[8] = {};
      const h2* wp = WihP2 + (size_t)(kh*32)*512 + jo*8;
#pragma unroll 16
      for (int kp = 0; kp < 32; ++kp) {
        const f16* w8 = (const f16*)(wp + (size_t)kp*512);
        f16x8 wlo = *(const f16x8*)w8;
        f16x8 whi = *(const f16x8*)(w8 + 8);
        h2 zv = zgP[kh*32 + kp];
        h2 p0; p0.x = wlo[0]; p0.y = wlo[1];
        h2 p1; p1.x = wlo[2]; p1.y = wlo[3];
        h2 p2; p2.x = wlo[4]; p2.y = wlo[5];
        h2 p3; p3.x = wlo[6]; p3.y = wlo[7];
        h2 p4; p4.x = whi[0]; p4.y = whi[1];
        h2 p5; p5.x = whi[2]; p5.y = whi[3];
        h2 p6; p6.x = whi[4]; p6.y = whi[5];
        h2 p7; p7.x = whi[6]; p7.y = whi[7];
        a[0] = fdot2(p0, zv, a[0]); a[1] = fdot2(p1, zv, a[1]);
        a[2] = fdot2(p2, zv, a[2]); a[3] = fdot2(p3, zv, a[3]);
        a[4] = fdot2(p4, zv, a[4]); a[5] = fdot2(p5, zv, a[5]);
        a[6] = fdot2(p6, zv, a[6]); a[7] = fdot2(p7, zv, a[7]);
      }
      const f16* wp2 = WhhT + (size_t)(kh*16)*512 + jo*8;
      const float* hp = &h[kh*16];
#pragma unroll
      for (int k = 0; k < 16; ++k) {
        float hk = hp[k];
        f16x8 wv = *(const f16x8*)&wp2[(size_t)k*512];
#pragma unroll
        for (int cN = 0; cN < 8; ++cN) a[cN] += hk * (float)wv[cN];
      }
#pragma unroll
      for (int cN = 0; cN < 8; ++cN) pG[kh][jo*8 + cN] = a[cN];
    }
    __syncthreads();
    if (tid < 128) {  // Stage H: LSTM cell (gate order i,f,g,o)
      float gi2 = biasS[tid], gf2 = biasS[128+tid], gg2 = biasS[256+tid], go2 = biasS[384+tid];
#pragma unroll
      for (int s = 0; s < 8; ++s) {
        gi2 += pG[s][tid];       gf2 += pG[s][128+tid];
        gg2 += pG[s][256+tid];   go2 += pG[s][384+tid];
      }
      float ii = sigm_f(gi2), ff = sigm_f(gf2), gg = tanh_f(gg2), oo = sigm_f(go2);
      float cn = ff * c[tid] + ii * gg;
      float hn = oo * tanh_f(cn);
      c[tid] = cn; h[tid] = hn;
      Hy[((size_t)row*BB + b)*256 + dir*128 + tid] = hn;
    }
    __syncthreads();
  }
}

// ---------------------------------------------------------------------------
// Answer pointer network (unchanged). 16 WGs, 256 threads, 2 steps.
// ---------------------------------------------------------------------------
__global__ __launch_bounds__(256) void ptr_net(
    const float* __restrict__ Hq,    // [48,16,256]
    const float* __restrict__ Hs,    // [256,16,256]
    const float* __restrict__ attp,  // [256,16,128]
    const float* __restrict__ WaaT,  // [128][128]
    const float* __restrict__ wbeta, // [128]
    const float* __restrict__ WahT,  // [256][128]
    const float* __restrict__ bah,
    const float* __restrict__ WacT,
    const float* __restrict__ bac,
    const float* __restrict__ WihT,  // [256][512]
    const float* __restrict__ WhhT,  // [128][512]
    const float* __restrict__ bptr,  // [512]
    float* __restrict__ out) {       // [2,256,16]
  int b = blockIdx.x;
  int tid = threadIdx.x;
  __shared__ float qp[256], h[128], c[128], haa[128], pe2[256], wv[256], part[1024];
  __shared__ float red[1];
  {
    float acc = 0.0f;
#pragma unroll 8
    for (int q = 0; q < QQ; ++q) acc += Hq[((size_t)q*BB + b)*256 + tid];
    qp[tid] = acc * (1.0f/48.0f);
  }
  __syncthreads();
  if (tid < 128) {
    float ah = bah[tid], ac = bac[tid];
#pragma unroll 8
    for (int k = 0; k < 256; ++k) {
      ah += qp[k] * WahT[k*128 + tid];
      ac += qp[k] * WacT[k*128 + tid];
    }
    h[tid] = ah; c[tid] = ac;
  }
  __syncthreads();
  for (int step = 0; step < 2; ++step) {
    if (tid < 128) {
      float acc = 0.0f;
#pragma unroll 8
      for (int k = 0; k < 128; ++k) acc += h[k] * WaaT[k*128 + tid];
      haa[tid] = acc;
    }
    __syncthreads();
    {
      const float* ap = attp + (size_t)tid*BB*128 + b*128;
      float s = 0.0f;
#pragma unroll 8
      for (int k = 0; k < 128; ++k) s += wbeta[k] * tanh_f(ap[k] + haa[k]);
      pe2[tid] = __expf(s);
    }
    __syncthreads();
    if (tid < 64) {
      float s2 = pe2[tid] + pe2[tid+64] + pe2[tid+128] + pe2[tid+192];
#pragma unroll
      for (int off = 32; off; off >>= 1) s2 += __shfl_down(s2, off);
      if (tid == 0) red[0] = s2;
    }
    __syncthreads();
    float inv = fast_rcp(red[0]);
    out[((size_t)step*PP + tid)*BB + b] = pe2[tid] * inv;
    {
      float acc = 0.0f;
#pragma unroll 8
      for (int p2 = 0; p2 < PP; ++p2) acc += pe2[p2] * Hs[((size_t)p2*BB + b)*256 + tid];
      wv[tid] = acc * inv;
    }
    __syncthreads();
    {
      int jq = tid & 127, kh = tid >> 7;
      float a0=0,a1=0,a2=0,a3=0;
      const float* wp = WihT + (size_t)kh*128*512 + jq*4;
      const float* vp = &wv[kh*128];
#pragma unroll 16
      for (int k = 0; k < 128; ++k) {
        float4 w4 = *(const float4*)&wp[(size_t)k*512];
        float v = vp[k];
        a0 += v*w4.x; a1 += v*w4.y; a2 += v*w4.z; a3 += v*w4.w;
      }
      const float* wp2 = WhhT + (size_t)kh*64*512 + jq*4;
      const float* hp = &h[kh*64];
#pragma unroll
      for (int k = 0; k < 64; ++k) {
        float4 w4 = *(const float4*)&wp2[(size_t)k*512];
        float v = hp[k];
        a0 += v*w4.x; a1 += v*w4.y; a2 += v*w4.z; a3 += v*w4.w;
      }
      part[kh*512 + jq*4 + 0] = a0; part[kh*512 + jq*4 + 1] = a1;
      part[kh*512 + jq*4 + 2] = a2; part[kh*512 + jq*4 + 3] = a3;
    }
    __syncthreads();
    if (tid < 128) {
      float gii = bptr[tid]     + part[tid]     + part[512+tid];
      float gff = bptr[128+tid] + part[128+tid] + part[640+tid];
      float ggg = bptr[256+tid] + part[256+tid] + part[768+tid];
      float goo = bptr[384+tid] + part[384+tid] + part[896+tid];
      float ii = sigm_f(gii), ff = sigm_f(gff), gg = tanh_f(ggg), oo = sigm_f(goo);
      float cn = ff * c[tid] + ii * gg;
      h[tid] = oo * tanh_f(cn); c[tid] = cn;
    }
    __syncthreads();
  }
}

// ---------------------------------------------------------------------------
extern "C" void kernel_launch(void* const* d_in, const int* in_sizes, int n_in,
                              void* d_out, int out_size, void* d_ws, size_t ws_size,
                              hipStream_t stream) {
  const float* p_inp  = (const float*)d_in[0];
  const float* q_inp  = (const float*)d_in[1];
  const float* g0_Wih = (const float*)d_in[2];
  const float* g0_Whh = (const float*)d_in[3];
  const float* g0_bih = (const float*)d_in[4];
  const float* g0_bhh = (const float*)d_in[5];
  const float* g1_Wih = (const float*)d_in[6];
  const float* g1_Whh = (const float*)d_in[7];
  const float* g1_bih = (const float*)d_in[8];
  const float* g1_bhh = (const float*)d_in[9];
  const float* g2_Wih = (const float*)d_in[10];
  const float* g2_Whh = (const float*)d_in[11];
  const float* g2_bih = (const float*)d_in[12];
  const float* g2_bhh = (const float*)d_in[13];
  const float* Wq     = (const float*)d_in[14];
  const float* Wp     = (const float*)d_in[15];
  const float* Wh     = (const float*)d_in[16];
  const float* w_alpha= (const float*)d_in[17];
  const float* Wg_m   = (const float*)d_in[18];
  const float* m_Wih  = (const float*)d_in[19];
  const float* m_Whh  = (const float*)d_in[20];
  const float* m_b    = (const float*)d_in[21];
  const float* Wsp    = (const float*)d_in[22];
  const float* Wsh    = (const float*)d_in[23];
  const float* w_gamma= (const float*)d_in[24];
  const float* Wg_s   = (const float*)d_in[25];
  const float* s_Wih  = (const float*)d_in[26];
  const float* s_Whh  = (const float*)d_in[27];
  const float* s_b    = (const float*)d_in[28];
  const float* Wal    = (const float*)d_in[29];
  const float* Waa    = (const float*)d_in[30];
  const float* w_beta = (const float*)d_in[31];
  const float* Wah    = (const float*)d_in[32];
  const float* bah    = (const float*)d_in[33];
  const float* Wac    = (const float*)d_in[34];
  const float* bac    = (const float*)d_in[35];
  const float* pt_Wih = (const float*)d_in[36];
  const float* pt_Whh = (const float*)d_in[37];
  const float* pt_b   = (const float*)d_in[38];

  float* ws = (float*)d_ws;
  size_t o = 0;
  auto alloc = [&](size_t n) { float* p = ws + o; o += n; return p; };
  // fp32 transposes (pointer net)
  float* WaaT   = alloc(16384);
  float* WahT   = alloc(32768);
  float* WacT   = alloc(32768);
  float* ptWihT = alloc(131072);
  float* ptWhhT = alloc(65536);
  // GRU f16 k-major weights
  f16* g0WhhH = (f16*)alloc(24576);
  f16* g1WhhH = (f16*)alloc(24576);
  f16* g2WhhH = (f16*)alloc(24576);
  // attn weights: Wih pair-packed h2, Whh/Whid k-major f16
  h2*  mWihP2 = (h2*)alloc(131072);   // [256kp][512j]
  f16* mWhhT  = (f16*)alloc(32768);   // [128k][512j]
  f16* mWhidT = (f16*)alloc(8192);    // [128k][128j]
  h2*  sWihP2 = (h2*)alloc(131072);
  f16* sWhhT  = (f16*)alloc(32768);
  f16* sWhidT = (f16*)alloc(8192);
  // persistent activations
  float* Hp  = alloc(1048576);   // [256,16,256]
  float* Hq_ = alloc(196608);    // [48,16,256]
  float* Hr  = alloc(1048576);
  float* Hs_ = alloc(1048576);
  // phase-reused region
  float* A = alloc(6225920);
  // GRU views
  float* gi_p = A;                 // [2,256,16,384] (layer0 uses [256,16,384])
  float* gi_q = A + 3145728;       // [2,48,16,384]
  float* hA_p = A + 3735552;       // [2,256,16,128]
  float* hB_p = A + 4784128;
  float* hA_q = A + 5832704;       // [2,48,16,128]
  float* hB_q = A + 6029312;       // ends 6225920
  // match views
  float* attq   = A;                    // [48,16,128] fp32 @0
  float* Xp     = A + 98304;            // [256,16,128]
  float* XgM    = A + 622592;           // [256,16,512] ends 2719744
  f16*   attqTH = (f16*)(A + 2719744);  // [16,128,48]  (49152 floats)
  f16*   HqU16  = (f16*)(A + 2768896);  // [16,48,768]  (294912 floats) ends 3063808
  // self views
  float* XgS     = A;                    // [256,16,512] @0 ends 2097152
  float* attsp   = A + 2097152;          // [256,16,128] ends 2621440
  f16*   attspTH = (f16*)(A + 2621440);  // [16,128,256] (262144 floats) ends 2883584
  f16*   HrU16   = (f16*)(A + 2883584);  // [16,256,768] (1572864 floats) ends 4456448
  // pointer view
  float* attp = A;                       // [256,16,128]

  // 1. fp32 transposes (pointer net weights)
  TDescs tds;
  tds.d[0] = { Waa,    WaaT,   128, 128, 128, 0 };
  tds.d[1] = { Wah,    WahT,   128, 256, 256, 0 };
  tds.d[2] = { Wac,    WacT,   128, 256, 256, 0 };
  tds.d[3] = { pt_Wih, ptWihT, 512, 256, 256, 0 };
  tds.d[4] = { pt_Whh, ptWhhT, 512, 128, 128, 0 };
  transpose_many<<<dim3(512, 5), 256, 0, stream>>>(tds);

  // 2. f16 k-major converts (GRU Whh ×3, attn Whh/Whid ×2 phases)
  HDescs hds;
  hds.d[0] = { g0_Whh, g0WhhH, 384, 128, 128 };
  hds.d[1] = { g1_Whh, g1WhhH, 384, 128, 128 };
  hds.d[2] = { g2_Whh, g2WhhH, 384, 128, 128 };
  hds.d[3] = { m_Whh,  mWhhT,  512, 128, 128 };
  hds.d[4] = { Wh,     mWhidT, 128, 128, 128 };
  hds.d[5] = { s_Whh,  sWhhT,  512, 128, 128 };
  hds.d[6] = { Wsh,    sWhidT, 128, 128, 128 };
  conv_w16_many<<<dim3(256, 7), 256, 0, stream>>>(hds);

  // 3. Wih k-pair packs for dot2
  QDescs qds;
  qds.d[0] = { m_Wih, mWihP2, 512, 512, 512 };
  qds.d[1] = { s_Wih, sWihP2, 512, 512, 512 };
  pack_pairs_many<<<dim3(512, 2), 256, 0, stream>>>(qds);

  // 4. GRU encoder
  gemm_nt<<<dim3(64, 6),  256, 0, stream>>>(p_inp, 556, g0_Wih, 556, g0_bih, gi_p, 384, 556);
  gemm_nt<<<dim3(12, 6),  256, 0, stream>>>(q_inp, 556, g0_Wih, 556, g0_bih, gi_q, 384, 556);
  gru_rec<<<16, 512, 0, stream>>>(gi_p, gi_q, g0WhhH, g0_bhh, hA_p, hA_q, nullptr, nullptr, 1, 0);
  gemm_nt<<<dim3(128, 6), 256, 0, stream>>>(hA_p, 128, g1_Wih, 128, g1_bih, gi_p, 384, 128);
  gemm_nt<<<dim3(24, 6),  256, 0, stream>>>(hA_q, 128, g1_Wih, 128, g1_bih, gi_q, 384, 128);
  gru_rec<<<16, 512, 0, stream>>>(gi_p, gi_q, g1WhhH, g1_bhh, hB_p, hB_q, nullptr, nullptr, 0, 0);
  gemm_nt<<<dim3(128, 6), 256, 0, stream>>>(hB_p, 128, g2_Wih, 128, g2_bih, gi_p, 384, 128);
  gemm_nt<<<dim3(24, 6),  256, 0, stream>>>(hB_q, 128, g2_Wih, 128, g2_bih, gi_q, 384, 128);
  gru_rec<<<16, 512, 0, stream>>>(gi_p, gi_q, g2WhhH, g2_bhh, hA_p, hA_q, Hp, Hq_, 0, 1);

  // 5. match-LSTM (passage attends over question)
  gemm_nt<<<dim3(12, 2), 256, 0, stream>>>(Hq_, 256, Wq, 256, nullptr, attq, 128, 256);
  gemm_nt<<<dim3(64, 2), 256, 0, stream>>>(Hp, 256, Wp, 256, nullptr, Xp, 128, 256);
  gemm_nt<<<dim3(64, 8), 256, 0, stream>>>(Hp, 256, Wg_m, 512, nullptr, XgM, 512, 256);
  gemm_f16u<<<dim3(12, 8), 256, 0, stream>>>(Hq_, 256, Wg_m + 256, 512, HqU16, QQ, 256);
  conv_hmemU<<<dim3(48, 16), 256, 0, stream>>>(Hq_, HqU16, 48);
  conv_attT<<<dim3(384), 256, 0, stream>>>(attq, attqTH, 48);
  attn_rec2<QQ><<<32, 512, 0, stream>>>(Hp, HqU16, attqTH, Xp, XgM, w_alpha,
                                        mWhidT, mWihP2, mWhhT, m_b, Hr);

  // 6. self-matching (Wmem == Wcur == Wsp: one projection serves both)
  gemm_nt<<<dim3(64, 2), 256, 0, stream>>>(Hr, 256, Wsp, 256, nullptr, attsp, 128, 256);
  gemm_nt<<<dim3(64, 8), 256, 0, stream>>>(Hr, 256, Wg_s, 512, nullptr, XgS, 512, 256);
  gemm_f16u<<<dim3(64, 8), 256, 0, stream>>>(Hr, 256, Wg_s + 256, 512, HrU16, PP, 256);
  conv_hmemU<<<dim3(256, 16), 256, 0, stream>>>(Hr, HrU16, 256);
  conv_attT<<<dim3(2048), 256, 0, stream>>>(attsp, attspTH, 256);
  attn_rec2<PP><<<32, 512, 0, stream>>>(Hr, HrU16, attspTH, attsp, XgS, w_gamma,
                                        sWhidT, sWihP2, sWhhT, s_b, Hs_);

  // 7. pointer network
  gemm_nt<<<dim3(64, 2), 256, 0, stream>>>(Hs_, 256, Wal, 256, nullptr, attp, 128, 256);
  ptr_net<<<16, 256, 0, stream>>>(Hq_, Hs_, attp, WaaT, w_beta, WahT, bah, WacT, bac,
                                  ptWihT, ptWhhT, pt_b, (float*)d_out);
}

// Round 9
// 8674.274 us; speedup vs baseline: 3.9725x; 1.0735x over previous
//
#include <hip/hip_runtime.h>

// ---------------------------------------------------------------------------
// R-Net forward on MI355X. Round 9: 16-wave attn WGs + LDS-hosted attT +
// LDS-resident GRU weights. The attn chain is pinned at ~60 GB/s effective
// per-CU streaming (8 waves); doubling waves doubles loads in flight.
//   P=256, Q=48, B=16, H=128, D=556, 2H=256, 3H=384, 4H=512
// ---------------------------------------------------------------------------

#define PP 256
#define QQ 48
#define BB 16

typedef _Float16 f16;
typedef f16 f16x4 __attribute__((ext_vector_type(4)));
typedef f16 f16x8 __attribute__((ext_vector_type(8)));
typedef f16 h2 __attribute__((ext_vector_type(2)));

__device__ __forceinline__ float fast_rcp(float x) { return __builtin_amdgcn_rcpf(x); }
__device__ __forceinline__ float tanh_f(float x) {
  float e = __expf(2.0f * x);
  return 1.0f - 2.0f * fast_rcp(1.0f + e);
}
__device__ __forceinline__ float sigm_f(float x) {
  return fast_rcp(1.0f + __expf(-x));
}
__device__ __forceinline__ float fdot2(h2 a, h2 b, float c) {
#if defined(__has_builtin)
#if __has_builtin(__builtin_amdgcn_fdot2)
  return __builtin_amdgcn_fdot2(a, b, c, false);
#else
  return c + (float)a.x*(float)b.x + (float)a.y*(float)b.y;
#endif
#else
  return c + (float)a.x*(float)b.x + (float)a.y*(float)b.y;
#endif
}

// ---------------------------------------------------------------------------
// Generic C[M,N] = A[M,K] @ W[N,K]^T + bias.  64x64 tiles, BK=16, 256 thr.
// ---------------------------------------------------------------------------
__global__ __launch_bounds__(256) void gemm_nt(
    const float* __restrict__ A, int lda,
    const float* __restrict__ W, int ldw,
    const float* __restrict__ bias,
    float* __restrict__ C, int ldc, int K) {
  __shared__ float As[64][17];
  __shared__ float Ws[64][17];
  int tid = threadIdx.x;
  int m0 = blockIdx.x * 64, n0 = blockIdx.y * 64;
  int lr = tid >> 2, lq = (tid & 3) * 4;
  int tr = tid >> 4, tc = tid & 15;
  float acc[4][4] = {};
  for (int k0 = 0; k0 < K; k0 += 16) {
    float4 av = {0,0,0,0}, wv = {0,0,0,0};
    if (k0 + lq < K) {
      av = *(const float4*)&A[(size_t)(m0 + lr) * lda + k0 + lq];
      wv = *(const float4*)&W[(size_t)(n0 + lr) * ldw + k0 + lq];
    }
    __syncthreads();
    As[lr][lq+0] = av.x; As[lr][lq+1] = av.y; As[lr][lq+2] = av.z; As[lr][lq+3] = av.w;
    Ws[lr][lq+0] = wv.x; Ws[lr][lq+1] = wv.y; Ws[lr][lq+2] = wv.z; Ws[lr][lq+3] = wv.w;
    __syncthreads();
#pragma unroll
    for (int kk = 0; kk < 16; ++kk) {
      float a4[4], b4[4];
#pragma unroll
      for (int i = 0; i < 4; ++i) a4[i] = As[tr*4+i][kk];
#pragma unroll
      for (int j = 0; j < 4; ++j) b4[j] = Ws[tc*4+j][kk];
#pragma unroll
      for (int i = 0; i < 4; ++i)
#pragma unroll
        for (int j = 0; j < 4; ++j) acc[i][j] += a4[i] * b4[j];
    }
  }
#pragma unroll
  for (int i = 0; i < 4; ++i) {
    int m = m0 + tr*4 + i;
#pragma unroll
    for (int j = 0; j < 4; ++j) {
      int n = n0 + tc*4 + j;
      C[(size_t)m * ldc + n] = acc[i][j] + (bias ? bias[n] : 0.0f);
    }
  }
}

// ---------------------------------------------------------------------------
// U GEMM writing f16 into the combined HmemU array (cols 256:768).
// ---------------------------------------------------------------------------
__global__ __launch_bounds__(256) void gemm_f16u(
    const float* __restrict__ A, int lda,
    const float* __restrict__ W, int ldw,
    f16* __restrict__ dst, int QMd, int K) {
  __shared__ float As[64][17];
  __shared__ float Ws[64][17];
  int tid = threadIdx.x;
  int m0 = blockIdx.x * 64, n0 = blockIdx.y * 64;
  int lr = tid >> 2, lq = (tid & 3) * 4;
  int tr = tid >> 4, tc = tid & 15;
  float acc[4][4] = {};
  for (int k0 = 0; k0 < K; k0 += 16) {
    float4 av = *(const float4*)&A[(size_t)(m0 + lr) * lda + k0 + lq];
    float4 wv = *(const float4*)&W[(size_t)(n0 + lr) * ldw + k0 + lq];
    __syncthreads();
    As[lr][lq+0] = av.x; As[lr][lq+1] = av.y; As[lr][lq+2] = av.z; As[lr][lq+3] = av.w;
    Ws[lr][lq+0] = wv.x; Ws[lr][lq+1] = wv.y; Ws[lr][lq+2] = wv.z; Ws[lr][lq+3] = wv.w;
    __syncthreads();
#pragma unroll
    for (int kk = 0; kk < 16; ++kk) {
      float a4[4], b4[4];
#pragma unroll
      for (int i = 0; i < 4; ++i) a4[i] = As[tr*4+i][kk];
#pragma unroll
      for (int j = 0; j < 4; ++j) b4[j] = Ws[tc*4+j][kk];
#pragma unroll
      for (int i = 0; i < 4; ++i)
#pragma unroll
        for (int j = 0; j < 4; ++j) acc[i][j] += a4[i] * b4[j];
    }
  }
#pragma unroll
  for (int i = 0; i < 4; ++i) {
    int m = m0 + tr*4 + i;
    int q = m >> 4, bb = m & 15;
#pragma unroll
    for (int j = 0; j < 4; ++j) {
      int n = n0 + tc*4 + j;
      dst[((size_t)bb*QMd + q)*768 + 256 + n] = (f16)acc[i][j];
    }
  }
}

// Hmem fp32 [QM,16,256] -> f16 cols 0:256 of HmemU [16][QM][768]
__global__ void conv_hmemU(const float* __restrict__ src, f16* __restrict__ dst, int QM) {
  int q = blockIdx.x, b = blockIdx.y, d = threadIdx.x;
  dst[((size_t)b*QM + q)*768 + d] = (f16)src[((size_t)q*BB + b)*256 + d];
}

// ---------------------------------------------------------------------------
// Batched fp32 transposes (pointer-net weights)
// ---------------------------------------------------------------------------
struct TDesc { const float* src; float* dst; int R, C, ld, off; };
struct TDescs { TDesc d[5]; };

__global__ __launch_bounds__(256) void transpose_many(TDescs ds) {
  TDesc d = ds.d[blockIdx.y];
  int idx = blockIdx.x * 256 + threadIdx.x;
  if (idx < d.R * d.C) {
    int r = idx / d.C, cc = idx % d.C;
    d.dst[(size_t)cc * d.R + r] = d.src[(size_t)r * d.ld + d.off + cc];
  }
}

// ---------------------------------------------------------------------------
// Batched fp32->fp16 k-major converts: dst[k*R + j] = src[j*ld + k]
// ---------------------------------------------------------------------------
struct HDesc { const float* src; f16* dst; int R, C, ld; };
struct HDescs { HDesc d[7]; };

__global__ __launch_bounds__(256) void conv_w16_many(HDescs ds) {
  HDesc d = ds.d[blockIdx.y];
  int idx = blockIdx.x * 256 + threadIdx.x;
  if (idx < d.R * d.C) {
    int j = idx / d.C, k = idx % d.C;
    d.dst[(size_t)k * d.R + j] = (f16)d.src[(size_t)j * d.ld + k];
  }
}

// ---------------------------------------------------------------------------
// k-pair packs for dot2: dst[kp*J + j] = h2(src[j*ld + 2kp], src[j*ld + 2kp+1])
// ---------------------------------------------------------------------------
struct QDesc { const float* src; h2* dst; int J, K, ld; };
struct QDescs { QDesc d[2]; };

__global__ __launch_bounds__(256) void pack_pairs_many(QDescs ds) {
  QDesc d = ds.d[blockIdx.y];
  int KP = d.K >> 1;
  int idx = blockIdx.x * 256 + threadIdx.x;
  if (idx < KP * d.J) {
    int kp = idx / d.J, j = idx % d.J;
    h2 v;
    v.x = (f16)d.src[(size_t)j*d.ld + 2*kp];
    v.y = (f16)d.src[(size_t)j*d.ld + 2*kp + 1];
    d.dst[(size_t)kp*d.J + j] = v;
  }
}

// att fp32 [QM,16,128] -> f16 [16][128][QM]
__global__ __launch_bounds__(256) void conv_attT(
    const float* __restrict__ src, f16* __restrict__ dst, int QM) {
  int idx = blockIdx.x * 256 + threadIdx.x;
  if (idx < 16*128*QM) {
    int q = idx % QM, h = (idx / QM) & 127, b = idx / (QM*128);
    dst[idx] = (f16)src[((size_t)q*BB + b)*128 + h];
  }
}

// ---------------------------------------------------------------------------
// GRU recurrence: WhhH LDS-RESIDENT (96KB, loaded once). 16 WGs, 512 threads.
// ---------------------------------------------------------------------------
__global__ __launch_bounds__(512, 1) void gru_rec(
    const float* __restrict__ gi_p, const float* __restrict__ gi_q,
    const f16* __restrict__ WhhH,   // [128][384] k-major fp16
    const float* __restrict__ bhh,  // [384]
    float* __restrict__ out_p, float* __restrict__ out_q,
    float* __restrict__ Hp, float* __restrict__ Hq,
    int mode0, int finalmode) {
  int x = blockIdx.x;
  int seq = x >> 3, dir = (x >> 2) & 1, bg = x & 3;
  int T = seq ? QQ : PP;
  const float* gi = seq ? gi_q : gi_p;
  float* out = seq ? out_q : out_p;
  float* Hf  = seq ? Hq   : Hp;
  int b0 = bg * 4;
  int tid = threadIdx.x;
  __shared__ f16 whhS[128*384];        // 96KB resident weights
  __shared__ float hs[4][128];
  __shared__ float gpart[4][4][384];
  for (int i = tid; i < 128*384/8; i += 512)
    *(f16x8*)&whhS[i*8] = *(const f16x8*)&WhhH[(size_t)i*8];
  if (tid < 256) { ((float*)hs)[tid] = 0.0f; ((float*)hs)[256+tid] = 0.0f; }
  __syncthreads();
  int ks = tid / 96;
  int jq = (tid % 96) * 4;
  int gb = tid >> 7, gj = tid & 127;
  for (int t = 0; t < T; ++t) {
    if (tid < 384) {
      float a[4][4] = {};
      const f16* wp = whhS + (size_t)ks*32*384 + jq;
      const int kb = ks*32;
#pragma unroll 8
      for (int k = 0; k < 32; ++k) {
        f16x4 wv = *(const f16x4*)&wp[(size_t)k*384];
        float w0 = (float)wv[0], w1 = (float)wv[1], w2 = (float)wv[2], w3 = (float)wv[3];
#pragma unroll
        for (int bb = 0; bb < 4; ++bb) {
          float hv = hs[bb][kb + k];
          a[bb][0] += hv*w0; a[bb][1] += hv*w1; a[bb][2] += hv*w2; a[bb][3] += hv*w3;
        }
      }
#pragma unroll
      for (int bb = 0; bb < 4; ++bb) {
        gpart[ks][bb][jq+0]=a[bb][0]; gpart[ks][bb][jq+1]=a[bb][1];
        gpart[ks][bb][jq+2]=a[bb][2]; gpart[ks][bb][jq+3]=a[bb][3];
      }
    }
    __syncthreads();
    {
      size_t base;
      if (mode0) {
        int girow = dir ? (T-1-t) : t;
        base = ((size_t)girow*BB + b0+gb)*384;
      } else {
        base = (((size_t)dir*T + t)*BB + b0+gb)*384;
      }
      float ghr = bhh[gj]     + gpart[0][gb][gj]     + gpart[1][gb][gj]     + gpart[2][gb][gj]     + gpart[3][gb][gj];
      float ghz = bhh[128+gj] + gpart[0][gb][128+gj] + gpart[1][gb][128+gj] + gpart[2][gb][128+gj] + gpart[3][gb][128+gj];
      float ghn = bhh[256+gj] + gpart[0][gb][256+gj] + gpart[1][gb][256+gj] + gpart[2][gb][256+gj] + gpart[3][gb][256+gj];
      float gr = gi[base + gj], gz = gi[base + 128 + gj], gn = gi[base + 256 + gj];
      float r = sigm_f(gr + ghr);
      float z = sigm_f(gz + ghz);
      float n = tanh_f(gn + r * ghn);
      float h2v = (1.0f - z) * n + z * hs[gb][gj];
      hs[gb][gj] = h2v;
      if (finalmode) {
        int orow = dir ? (T-1-t) : t;
        Hf[((size_t)orow*BB + b0+gb)*256 + dir*128 + gj] = h2v;
      } else {
        out[(((size_t)dir*T + t)*BB + b0+gb)*128 + gj] = h2v;
      }
    }
    __syncthreads();
  }
}

// ---------------------------------------------------------------------------
// Gated additive-attention LSTM, round 9: 1024 threads (16 waves), attT in
// LDS (both variants), HmemU in LDS for QM=48. 9 barriers/step.
// ---------------------------------------------------------------------------
template<int QM>
__global__ __launch_bounds__(1024, 1) void attn_rec3(
    const float* __restrict__ Hseq,   // [256,16,256] fp32
    const f16*  __restrict__ HmemU,   // [16][QM][768] f16 ([Hmem | U])
    const f16*  __restrict__ attT,    // [16][128][QM] f16
    const float* __restrict__ Xcur,   // [256,16,128]
    const float* __restrict__ Xg,     // [256,16,512]
    const float* __restrict__ watt,   // [128]
    const f16*  __restrict__ WhidT,   // [128k][128j]
    const h2*   __restrict__ WihP2,   // [256kp][512j] pair-packed
    const f16*  __restrict__ WhhT,    // [128k][512j]
    const float* __restrict__ bias,   // [512]
    float* __restrict__ Hy) {         // [256,16,256]
  constexpr bool HOST = (QM == QQ);
  constexpr int QP  = HOST ? 64 : 256;   // padded mem length (pow2)
  constexpr int HS  = 1024 / QP;         // 16 or 4 h-slices in score stage
  constexpr int hl  = 128 / HS;          // 8 or 32
  constexpr int hsh = HOST ? 6 : 8;      // log2(QP)
  constexpr int QR  = QM / 8;            // q rows per split in stage DE
  int dir = blockIdx.x >> 4, b = blockIdx.x & 15;
  int tid = threadIdx.x;
  __shared__ f16 attSL[128*QM];          // hosted attT (12KB / 64KB)
  __shared__ f16 humSL[HOST ? QQ*768 : 8];
  __shared__ float h[128], c[128], xh[128], xc[128], wa[128];
  __shared__ float peS[QP], zx[256];
  __shared__ h2 zgP[256];
  __shared__ float pA[8][128];
  __shared__ float pB[1024];
  __shared__ float pDE[8][768];
  __shared__ float pG[8][512];
  __shared__ float biasS[512];
  __shared__ float red[1];
  if (tid < 128) { h[tid] = 0.0f; c[tid] = 0.0f; wa[tid] = watt[tid]; }
  if (tid < 512) biasS[tid] = bias[tid];
  const f16* attb = attT  + (size_t)b*128*QM;
  const f16* humb = HmemU + (size_t)b*QM*768;
  for (int i = tid; i < 128*QM/8; i += 1024)
    *(f16x8*)&attSL[i*8] = *(const f16x8*)&attb[(size_t)i*8];
  if constexpr (HOST) {
    for (int i = tid; i < QQ*768/8; i += 1024)
      *(f16x8*)&humSL[i*8] = *(const f16x8*)&humb[(size_t)i*8];
  }
  __syncthreads();
  for (int t = 0; t < PP; ++t) {
    int row = dir ? (PP-1-t) : t;
    {  // Stage A: hW partials (8-way k-split) + xc / zx loads
      int j = tid & 127, kh = tid >> 7;
      float acc = 0.0f;
      const f16* wp = WhidT + (size_t)kh*16*128 + j;
      const float* hp = &h[kh*16];
#pragma unroll
      for (int k = 0; k < 16; ++k) acc += (float)wp[(size_t)k*128] * hp[k];
      pA[kh][j] = acc;
      if (tid < 128) xc[tid] = Xcur[((size_t)row*BB + b)*128 + tid];
      else if (tid < 192) *(float4*)&zx[(tid-128)*4] =
          *(const float4*)&Hseq[((size_t)row*BB + b)*256 + (tid-128)*4];
    }
    __syncthreads();
    if (tid < 128) {  // Stage A2: xh combine
      float a = xc[tid];
#pragma unroll
      for (int i = 0; i < 8; ++i) a += pA[i][tid];
      xh[tid] = a;
    }
    __syncthreads();
    {  // Stage B: scores from LDS attT + xh
      int q = tid & (QP-1), hh = tid >> hsh;
      float acc = 0.0f;
      if (q < QM) {
        const f16* ap = attSL + q;
        int h0 = hh * hl;
#pragma unroll 8
        for (int i = 0; i < hl; ++i) {
          int hx = h0 + i;
          acc += wa[hx] * tanh_f((float)ap[(size_t)hx*QM] + xh[hx]);
        }
      }
      pB[hh*QP + q] = acc;
    }
    __syncthreads();
    if (tid < 64) {  // Stage C: combine score partials, exp, sum
      float lsum = 0.0f;
      for (int q2 = tid; q2 < QP; q2 += 64) {
        float s = 0.0f;
#pragma unroll
        for (int i = 0; i < HS; ++i) s += pB[i*QP + q2];
        float e = (q2 < QM) ? __expf(s) : 0.0f;
        peS[q2] = e; lsum += e;
      }
#pragma unroll
      for (int off = 32; off; off >>= 1) lsum += __shfl_down(lsum, off);
      if (tid == 0) red[0] = lsum;
    }
    __syncthreads();
    {  // Stage DE (merged): [w | u_num] = sum_q pe[q] * HmemU[q][0:768]
      int oc = tid & 127, qs = tid >> 7;
      if (oc < 96) {
        float a[8] = {};
        if constexpr (HOST) {
          const f16* hp = &humSL[(size_t)(qs*QR)*768 + oc*8];
#pragma unroll
          for (int i = 0; i < QR; ++i) {
            float pv = peS[qs*QR + i];
            f16x8 mv = *(const f16x8*)&hp[(size_t)i*768];
#pragma unroll
            for (int cN = 0; cN < 8; ++cN) a[cN] += pv * (float)mv[cN];
          }
        } else {
          const f16* hp = humb + (size_t)(qs*QR)*768 + oc*8;
#pragma unroll 8
          for (int i = 0; i < QR; ++i) {
            float pv = peS[qs*QR + i];
            f16x8 mv = *(const f16x8*)&hp[(size_t)i*768];
#pragma unroll
            for (int cN = 0; cN < 8; ++cN) a[cN] += pv * (float)mv[cN];
          }
        }
#pragma unroll
        for (int cN = 0; cN < 8; ++cN) pDE[qs][oc*8 + cN] = a[cN];
      }
    }
    __syncthreads();
    if (tid < 256) {  // Stage F: zg pair = z * sigmoid(Xg + u), packed h2
      float invd = fast_rcp(red[0]);
      int j0 = 2*tid;
      float u0 = 0.0f, u1 = 0.0f;
#pragma unroll
      for (int s = 0; s < 8; ++s) { u0 += pDE[s][256+j0]; u1 += pDE[s][257+j0]; }
      u0 *= invd; u1 *= invd;
      float z0, z1;
      if (tid < 128) { z0 = zx[j0]; z1 = zx[j0+1]; }
      else {
        int d0 = j0 - 256;
        float w0 = 0.0f, w1 = 0.0f;
#pragma unroll
        for (int s = 0; s < 8; ++s) { w0 += pDE[s][d0]; w1 += pDE[s][d0+1]; }
        z0 = w0 * invd; z1 = w1 * invd;
      }
      float2 xg2 = *(const float2*)&Xg[((size_t)row*BB + b)*512 + j0];
      h2 p;
      p.x = (f16)(z0 * sigm_f(xg2.x + u0));
      p.y = (f16)(z1 * sigm_f(xg2.y + u1));
      zgP[tid] = p;
    }
    __syncthreads();
    {  // Stage G: gates = zg @ Wih^T (dot2) + h @ Whh^T; 4 cols/thread
      int jo = tid & 127, kh = tid >> 7;
      float a0=0,a1=0,a2=0,a3=0;
      const h2* wp = WihP2 + (size_t)(kh*32)*512 + jo*4;
#pragma unroll 8
      for (int kp = 0; kp < 32; ++kp) {
        f16x8 wv = *(const f16x8*)(const f16*)(wp + (size_t)kp*512);
        h2 zv = zgP[kh*32 + kp];
        h2 p0; p0.x = wv[0]; p0.y = wv[1];
        h2 p1; p1.x = wv[2]; p1.y = wv[3];
        h2 p2; p2.x = wv[4]; p2.y = wv[5];
        h2 p3; p3.x = wv[6]; p3.y = wv[7];
        a0 = fdot2(p0, zv, a0); a1 = fdot2(p1, zv, a1);
        a2 = fdot2(p2, zv, a2); a3 = fdot2(p3, zv, a3);
      }
      const f16* wp2 = WhhT + (size_t)(kh*16)*512 + jo*4;
      const float* hp = &h[kh*16];
#pragma unroll
      for (int k = 0; k < 16; ++k) {
        float hk = hp[k];
        f16x4 wv = *(const f16x4*)&wp2[(size_t)k*512];
        a0 += hk*(float)wv[0]; a1 += hk*(float)wv[1];
        a2 += hk*(float)wv[2]; a3 += hk*(float)wv[3];
      }
      pG[kh][jo*4+0]=a0; pG[kh][jo*4+1]=a1; pG[kh][jo*4+2]=a2; pG[kh][jo*4+3]=a3;
    }
    __syncthreads();
    if (tid < 128) {  // Stage H: LSTM cell (gate order i,f,g,o)
      float gi2 = biasS[tid], gf2 = biasS[128+tid], gg2 = biasS[256+tid], go2 = biasS[384+tid];
#pragma unroll
      for (int s = 0; s < 8; ++s) {
        gi2 += pG[s][tid];       gf2 += pG[s][128+tid];
        gg2 += pG[s][256+tid];   go2 += pG[s][384+tid];
      }
      float ii = sigm_f(gi2), ff = sigm_f(gf2), gg = tanh_f(gg2), oo = sigm_f(go2);
      float cn = ff * c[tid] + ii * gg;
      float hn = oo * tanh_f(cn);
      c[tid] = cn; h[tid] = hn;
      Hy[((size_t)row*BB + b)*256 + dir*128 + tid] = hn;
    }
    __syncthreads();
  }
}

// ---------------------------------------------------------------------------
// Answer pointer network (unchanged). 16 WGs, 256 threads, 2 steps.
// ---------------------------------------------------------------------------
__global__ __launch_bounds__(256) void ptr_net(
    const float* __restrict__ Hq,    // [48,16,256]
    const float* __restrict__ Hs,    // [256,16,256]
    const float* __restrict__ attp,  // [256,16,128]
    const float* __restrict__ WaaT,  // [128][128]
    const float* __restrict__ wbeta, // [128]
    const float* __restrict__ WahT,  // [256][128]
    const float* __restrict__ bah,
    const float* __restrict__ WacT,
    const float* __restrict__ bac,
    const float* __restrict__ WihT,  // [256][512]
    const float* __restrict__ WhhT,  // [128][512]
    const float* __restrict__ bptr,  // [512]
    float* __restrict__ out) {       // [2,256,16]
  int b = blockIdx.x;
  int tid = threadIdx.x;
  __shared__ float qp[256], h[128], c[128], haa[128], pe2[256], wv[256], part[1024];
  __shared__ float red[1];
  {
    float acc = 0.0f;
#pragma unroll 8
    for (int q = 0; q < QQ; ++q) acc += Hq[((size_t)q*BB + b)*256 + tid];
    qp[tid] = acc * (1.0f/48.0f);
  }
  __syncthreads();
  if (tid < 128) {
    float ah = bah[tid], ac = bac[tid];
#pragma unroll 8
    for (int k = 0; k < 256; ++k) {
      ah += qp[k] * WahT[k*128 + tid];
      ac += qp[k] * WacT[k*128 + tid];
    }
    h[tid] = ah; c[tid] = ac;
  }
  __syncthreads();
  for (int step = 0; step < 2; ++step) {
    if (tid < 128) {
      float acc = 0.0f;
#pragma unroll 8
      for (int k = 0; k < 128; ++k) acc += h[k] * WaaT[k*128 + tid];
      haa[tid] = acc;
    }
    __syncthreads();
    {
      const float* ap = attp + (size_t)tid*BB*128 + b*128;
      float s = 0.0f;
#pragma unroll 8
      for (int k = 0; k < 128; ++k) s += wbeta[k] * tanh_f(ap[k] + haa[k]);
      pe2[tid] = __expf(s);
    }
    __syncthreads();
    if (tid < 64) {
      float s2 = pe2[tid] + pe2[tid+64] + pe2[tid+128] + pe2[tid+192];
#pragma unroll
      for (int off = 32; off; off >>= 1) s2 += __shfl_down(s2, off);
      if (tid == 0) red[0] = s2;
    }
    __syncthreads();
    float inv = fast_rcp(red[0]);
    out[((size_t)step*PP + tid)*BB + b] = pe2[tid] * inv;
    {
      float acc = 0.0f;
#pragma unroll 8
      for (int p2 = 0; p2 < PP; ++p2) acc += pe2[p2] * Hs[((size_t)p2*BB + b)*256 + tid];
      wv[tid] = acc * inv;
    }
    __syncthreads();
    {
      int jq = tid & 127, kh = tid >> 7;
      float a0=0,a1=0,a2=0,a3=0;
      const float* wp = WihT + (size_t)kh*128*512 + jq*4;
      const float* vp = &wv[kh*128];
#pragma unroll 16
      for (int k = 0; k < 128; ++k) {
        float4 w4 = *(const float4*)&wp[(size_t)k*512];
        float v = vp[k];
        a0 += v*w4.x; a1 += v*w4.y; a2 += v*w4.z; a3 += v*w4.w;
      }
      const float* wp2 = WhhT + (size_t)kh*64*512 + jq*4;
      const float* hp = &h[kh*64];
#pragma unroll
      for (int k = 0; k < 64; ++k) {
        float4 w4 = *(const float4*)&wp2[(size_t)k*512];
        float v = hp[k];
        a0 += v*w4.x; a1 += v*w4.y; a2 += v*w4.z; a3 += v*w4.w;
      }
      part[kh*512 + jq*4 + 0] = a0; part[kh*512 + jq*4 + 1] = a1;
      part[kh*512 + jq*4 + 2] = a2; part[kh*512 + jq*4 + 3] = a3;
    }
    __syncthreads();
    if (tid < 128) {
      float gii = bptr[tid]     + part[tid]     + part[512+tid];
      float gff = bptr[128+tid] + part[128+tid] + part[640+tid];
      float ggg = bptr[256+tid] + part[256+tid] + part[768+tid];
      float goo = bptr[384+tid] + part[384+tid] + part[896+tid];
      float ii = sigm_f(gii), ff = sigm_f(gff), gg = tanh_f(ggg), oo = sigm_f(goo);
      float cn = ff * c[tid] + ii * gg;
      h[tid] = oo * tanh_f(cn); c[tid] = cn;
    }
    __syncthreads();
  }
}

// ---------------------------------------------------------------------------
extern "C" void kernel_launch(void* const* d_in, const int* in_sizes, int n_in,
                              void* d_out, int out_size, void* d_ws, size_t ws_size,
                              hipStream_t stream) {
  const float* p_inp  = (const float*)d_in[0];
  const float* q_inp  = (const float*)d_in[1];
  const float* g0_Wih = (const float*)d_in[2];
  const float* g0_Whh = (const float*)d_in[3];
  const float* g0_bih = (const float*)d_in[4];
  const float* g0_bhh = (const float*)d_in[5];
  const float* g1_Wih = (const float*)d_in[6];
  const float* g1_Whh = (const float*)d_in[7];
  const float* g1_bih = (const float*)d_in[8];
  const float* g1_bhh = (const float*)d_in[9];
  const float* g2_Wih = (const float*)d_in[10];
  const float* g2_Whh = (const float*)d_in[11];
  const float* g2_bih = (const float*)d_in[12];
  const float* g2_bhh = (const float*)d_in[13];
  const float* Wq     = (const float*)d_in[14];
  const float* Wp     = (const float*)d_in[15];
  const float* Wh     = (const float*)d_in[16];
  const float* w_alpha= (const float*)d_in[17];
  const float* Wg_m   = (const float*)d_in[18];
  const float* m_Wih  = (const float*)d_in[19];
  const float* m_Whh  = (const float*)d_in[20];
  const float* m_b    = (const float*)d_in[21];
  const float* Wsp    = (const float*)d_in[22];
  const float* Wsh    = (const float*)d_in[23];
  const float* w_gamma= (const float*)d_in[24];
  const float* Wg_s   = (const float*)d_in[25];
  const float* s_Wih  = (const float*)d_in[26];
  const float* s_Whh  = (const float*)d_in[27];
  const float* s_b    = (const float*)d_in[28];
  const float* Wal    = (const float*)d_in[29];
  const float* Waa    = (const float*)d_in[30];
  const float* w_beta = (const float*)d_in[31];
  const float* Wah    = (const float*)d_in[32];
  const float* bah    = (const float*)d_in[33];
  const float* Wac    = (const float*)d_in[34];
  const float* bac    = (const float*)d_in[35];
  const float* pt_Wih = (const float*)d_in[36];
  const float* pt_Whh = (const float*)d_in[37];
  const float* pt_b   = (const float*)d_in[38];

  float* ws = (float*)d_ws;
  size_t o = 0;
  auto alloc = [&](size_t n) { float* p = ws + o; o += n; return p; };
  // fp32 transposes (pointer net)
  float* WaaT   = alloc(16384);
  float* WahT   = alloc(32768);
  float* WacT   = alloc(32768);
  float* ptWihT = alloc(131072);
  float* ptWhhT = alloc(65536);
  // GRU f16 k-major weights
  f16* g0WhhH = (f16*)alloc(24576);
  f16* g1WhhH = (f16*)alloc(24576);
  f16* g2WhhH = (f16*)alloc(24576);
  // attn weights: Wih pair-packed h2, Whh/Whid k-major f16
  h2*  mWihP2 = (h2*)alloc(131072);   // [256kp][512j]
  f16* mWhhT  = (f16*)alloc(32768);   // [128k][512j]
  f16* mWhidT = (f16*)alloc(8192);    // [128k][128j]
  h2*  sWihP2 = (h2*)alloc(131072);
  f16* sWhhT  = (f16*)alloc(32768);
  f16* sWhidT = (f16*)alloc(8192);
  // persistent activations
  float* Hp  = alloc(1048576);   // [256,16,256]
  float* Hq_ = alloc(196608);    // [48,16,256]
  float* Hr  = alloc(1048576);
  float* Hs_ = alloc(1048576);
  // phase-reused region
  float* A = alloc(6225920);
  // GRU views
  float* gi_p = A;                 // [2,256,16,384] (layer0 uses [256,16,384])
  float* gi_q = A + 3145728;       // [2,48,16,384]
  float* hA_p = A + 3735552;       // [2,256,16,128]
  float* hB_p = A + 4784128;
  float* hA_q = A + 5832704;       // [2,48,16,128]
  float* hB_q = A + 6029312;       // ends 6225920
  // match views
  float* attq   = A;                    // [48,16,128] fp32 @0
  float* Xp     = A + 98304;            // [256,16,128]
  float* XgM    = A + 622592;           // [256,16,512] ends 2719744
  f16*   attqTH = (f16*)(A + 2719744);  // [16,128,48]  (49152 floats)
  f16*   HqU16  = (f16*)(A + 2768896);  // [16,48,768]  (294912 floats) ends 3063808
  // self views
  float* XgS     = A;                    // [256,16,512] @0 ends 2097152
  float* attsp   = A + 2097152;          // [256,16,128] ends 2621440
  f16*   attspTH = (f16*)(A + 2621440);  // [16,128,256] (262144 floats) ends 2883584
  f16*   HrU16   = (f16*)(A + 2883584);  // [16,256,768] (1572864 floats) ends 4456448
  // pointer view
  float* attp = A;                       // [256,16,128]

  // 1. fp32 transposes (pointer net weights)
  TDescs tds;
  tds.d[0] = { Waa,    WaaT,   128, 128, 128, 0 };
  tds.d[1] = { Wah,    WahT,   128, 256, 256, 0 };
  tds.d[2] = { Wac,    WacT,   128, 256, 256, 0 };
  tds.d[3] = { pt_Wih, ptWihT, 512, 256, 256, 0 };
  tds.d[4] = { pt_Whh, ptWhhT, 512, 128, 128, 0 };
  transpose_many<<<dim3(512, 5), 256, 0, stream>>>(tds);

  // 2. f16 k-major converts
  HDescs hds;
  hds.d[0] = { g0_Whh, g0WhhH, 384, 128, 128 };
  hds.d[1] = { g1_Whh, g1WhhH, 384, 128, 128 };
  hds.d[2] = { g2_Whh, g2WhhH, 384, 128, 128 };
  hds.d[3] = { m_Whh,  mWhhT,  512, 128, 128 };
  hds.d[4] = { Wh,     mWhidT, 128, 128, 128 };
  hds.d[5] = { s_Whh,  sWhhT,  512, 128, 128 };
  hds.d[6] = { Wsh,    sWhidT, 128, 128, 128 };
  conv_w16_many<<<dim3(256, 7), 256, 0, stream>>>(hds);

  // 3. Wih k-pair packs for dot2
  QDescs qds;
  qds.d[0] = { m_Wih, mWihP2, 512, 512, 512 };
  qds.d[1] = { s_Wih, sWihP2, 512, 512, 512 };
  pack_pairs_many<<<dim3(512, 2), 256, 0, stream>>>(qds);

  // 4. GRU encoder
  gemm_nt<<<dim3(64, 6),  256, 0, stream>>>(p_inp, 556, g0_Wih, 556, g0_bih, gi_p, 384, 556);
  gemm_nt<<<dim3(12, 6),  256, 0, stream>>>(q_inp, 556, g0_Wih, 556, g0_bih, gi_q, 384, 556);
  gru_rec<<<16, 512, 0, stream>>>(gi_p, gi_q, g0WhhH, g0_bhh, hA_p, hA_q, nullptr, nullptr, 1, 0);
  gemm_nt<<<dim3(128, 6), 256, 0, stream>>>(hA_p, 128, g1_Wih, 128, g1_bih, gi_p, 384, 128);
  gemm_nt<<<dim3(24, 6),  256, 0, stream>>>(hA_q, 128, g1_Wih, 128, g1_bih, gi_q, 384, 128);
  gru_rec<<<16, 512, 0, stream>>>(gi_p, gi_q, g1WhhH, g1_bhh, hB_p, hB_q, nullptr, nullptr, 0, 0);
  gemm_nt<<<dim3(128, 6), 256, 0, stream>>>(hB_p, 128, g2_Wih, 128, g2_bih, gi_p, 384, 128);
  gemm_nt<<<dim3(24, 6),  256, 0, stream>>>(hB_q, 128, g2_Wih, 128, g2_bih, gi_q, 384, 128);
  gru_rec<<<16, 512, 0, stream>>>(gi_p, gi_q, g2WhhH, g2_bhh, hA_p, hA_q, Hp, Hq_, 0, 1);

  // 5. match-LSTM (passage attends over question)
  gemm_nt<<<dim3(12, 2), 256, 0, stream>>>(Hq_, 256, Wq, 256, nullptr, attq, 128, 256);
  gemm_nt<<<dim3(64, 2), 256, 0, stream>>>(Hp, 256, Wp, 256, nullptr, Xp, 128, 256);
  gemm_nt<<<dim3(64, 8), 256, 0, stream>>>(Hp, 256, Wg_m, 512, nullptr, XgM, 512, 256);
  gemm_f16u<<<dim3(12, 8), 256, 0, stream>>>(Hq_, 256, Wg_m + 256, 512, HqU16, QQ, 256);
  conv_hmemU<<<dim3(48, 16), 256, 0, stream>>>(Hq_, HqU16, 48);
  conv_attT<<<dim3(384), 256, 0, stream>>>(attq, attqTH, 48);
  attn_rec3<QQ><<<32, 1024, 0, stream>>>(Hp, HqU16, attqTH, Xp, XgM, w_alpha,
                                         mWhidT, mWihP2, mWhhT, m_b, Hr);

  // 6. self-matching (Wmem == Wcur == Wsp: one projection serves both)
  gemm_nt<<<dim3(64, 2), 256, 0, stream>>>(Hr, 256, Wsp, 256, nullptr, attsp, 128, 256);
  gemm_nt<<<dim3(64, 8), 256, 0, stream>>>(Hr, 256, Wg_s, 512, nullptr, XgS, 512, 256);
  gemm_f16u<<<dim3(64, 8), 256, 0, stream>>>(Hr, 256, Wg_s + 256, 512, HrU16, PP, 256);
  conv_hmemU<<<dim3(256, 16), 256, 0, stream>>>(Hr, HrU16, 256);
  conv_attT<<<dim3(2048), 256, 0, stream>>>(attsp, attspTH, 256);
  attn_rec3<PP><<<32, 1024, 0, stream>>>(Hr, HrU16, attspTH, attsp, XgS, w_gamma,
                                         sWhidT, sWihP2, sWhhT, s_b, Hs_);

  // 7. pointer network
  gemm_nt<<<dim3(64, 2), 256, 0, stream>>>(Hs_, 256, Wal, 256, nullptr, attp, 128, 256);
  ptr_net<<<16, 256, 0, stream>>>(Hq_, Hs_, attp, WaaT, w_beta, WahT, bah, WacT, bac,
                                  ptWihT, ptWhhT, pt_b, (float*)d_out);
}